// Round 4
// baseline (450.747 us; speedup 1.0000x reference)
//
#include <hip/hip_runtime.h>
#include <hip/hip_bf16.h>
#include <math.h>

#define B_  4
#define S_  2048
#define D_  768
#define H_  12
#define HD_ 64
#define DF_ 3072
#define BS_ (B_*S_)

// 0.125 (hd^-0.5) * log2(e): folded into Q projection so softmax runs in exp2 domain
#define QSCALE 0.18033688011112042f

typedef __attribute__((ext_vector_type(8))) short short8;
typedef __attribute__((ext_vector_type(4))) float f32x4;

__device__ __forceinline__ unsigned short f2b(float f){
    unsigned int x = __float_as_uint(f);
    return (unsigned short)((x + 0x7fffu + ((x >> 16) & 1u)) >> 16);   // RNE
}
__device__ __forceinline__ float b2f(unsigned short u){
    return __uint_as_float(((unsigned int)u) << 16);
}

typedef __attribute__((address_space(1))) void gvoid_t;
typedef __attribute__((address_space(3))) void lvoid_t;
typedef __attribute__((address_space(3))) unsigned char lchar_t;
__device__ __forceinline__ void gload_lds16(const unsigned short* g, unsigned short* l){
    __builtin_amdgcn_global_load_lds((gvoid_t*)g, (lvoid_t*)l, 16, 0, 0);
}
__device__ __forceinline__ unsigned ldsaddr(const void* p){
    return (unsigned)(size_t)(lchar_t*)(lvoid_t*)p;
}
// inline-asm ds_read_b128: bypasses compiler alias analysis so NO conservative
// vmcnt(0) drains get inserted against outstanding global_load_lds (rule #18 —
// must pair with explicit lgkmcnt(0) + sched_barrier(0) before the consuming MFMA).
#define DSR(dst, addr, OFF) \
    asm volatile("ds_read_b128 %0, %1 offset:" #OFF : "=v"(dst) : "v"(addr))

// ---------------------------------------------------------------- merged prep
// grid sections: [0,24576) cvt x | 4*576 DxD transposes | 2304 W1 | 2304 W2 | 9 bias
__global__ __launch_bounds__(256) void prep_kernel(
    const float* __restrict__ x,
    const float* __restrict__ Wq, const float* __restrict__ Wk,
    const float* __restrict__ Wv, const float* __restrict__ Wo,
    const float* __restrict__ W1, const float* __restrict__ W2,
    const float* __restrict__ bq, const float* __restrict__ bk, const float* __restrict__ bv,
    unsigned short* __restrict__ xb, unsigned short* __restrict__ wqkvT,
    unsigned short* __restrict__ woT, unsigned short* __restrict__ w1T,
    unsigned short* __restrict__ w2T, float* __restrict__ bqkv)
{
    const int NCVT = (BS_*D_)/256;         // 24576
    int bid = blockIdx.x;
    if (bid < NCVT){
        int i = bid*256 + threadIdx.x;
        xb[i] = f2b(x[i]);
        return;
    }
    bid -= NCVT;
    __shared__ float t[32][33];
    const float* src; unsigned short* dst; int K, N, bx, by;
    if (bid < 4*576){
        int wsel = bid / 576, tt = bid % 576;
        bx = tt % 24; by = tt / 24; K = D_; N = D_;
        src = (wsel==0)?Wq:(wsel==1)?Wk:(wsel==2)?Wv:Wo;
        dst = (wsel<3) ? (wqkvT + (size_t)wsel*D_*D_) : woT;
    } else if (bid < 4*576 + 2304){
        int tt = bid - 4*576; bx = tt % 96; by = tt / 96; K = D_; N = DF_; src = W1; dst = w1T;
    } else if (bid < 4*576 + 2*2304){
        int tt = bid - 4*576 - 2304; bx = tt % 24; by = tt / 24; K = DF_; N = D_; src = W2; dst = w2T;
    } else {
        int i = (bid - (4*576 + 2*2304))*256 + threadIdx.x;
        if (i < 3*D_) bqkv[i] = (i < D_) ? bq[i] : (i < 2*D_) ? bk[i-D_] : bv[i-2*D_];
        return;
    }
    int tx = threadIdx.x & 31, ty = threadIdx.x >> 5;
    #pragma unroll
    for (int i = 0; i < 4; ++i)
        t[ty + i*8][tx] = src[(size_t)(by*32 + ty + i*8) * N + bx*32 + tx];
    __syncthreads();
    #pragma unroll
    for (int i = 0; i < 4; ++i)
        dst[(size_t)(bx*32 + ty + i*8) * K + by*32 + tx] = f2b(t[tx][ty + i*8]);
}

// ---------------------------------------------------------------- GEMM: 256x256 tile, full-dbuf 2-phase
// C[M,N] = A[M,K] @ Bt[N,K]^T + bias. BM=BN=256, BK=64, 512 threads, 8 waves 2Mx4N (128x64/wave).
// Minimum-2-phase pipeline (T3 recipe): at tile t start, stage the ENTIRE tile t+1 (4 half-tiles,
// 8 global_load_lds) into the OPPOSITE buffer -> zero intra-tile RAW hazards -> NO intra-tile
// barriers. Compute tile t in 4 ds_read/MFMA clusters separated only by lgkmcnt(0)+sched_barrier(0)
// (rule #18: asm ds_read needs the explicit pair; keeps compiler from inserting vmcnt drains).
// ONE vmcnt(0)+s_barrier per tile; the staged loads age a full tile (~2500+ cyc of MFMA+LDS) before
// the wait, so even vmcnt(0) has slack >> HBM latency. No barriers between clusters -> the 2
// waves/SIMD drift and overlap MFMA with ds_read across waves (m114 implicit overlap).
// LDS: 2 buffers x (A 32KB + B 32KB) = 128KB, laid out as [buf][kc-half][8192 shorts]; each
// half-tile = 128 row-pair lines of 128B with chunk-XOR swizzle (q^line)&7 (conflict-free, 0 meas.).
// act: 0 none (fp32 partial out, split-K via blockIdx.z), 1 tanh-GELU->bf16, 2 QKV-mode.
__global__ __launch_bounds__(512, 2) void gemm_tn(
    const unsigned short* __restrict__ A,
    const unsigned short* __restrict__ Bt,
    const float* __restrict__ bias,
    float* __restrict__ Cf,
    unsigned short* __restrict__ Cb,
    unsigned short* __restrict__ vtg,
    int M, int N, int K, int klen, int act)
{
    __shared__ __align__(16) unsigned short Asl[2*2*8192];
    __shared__ __align__(16) unsigned short Bsl[2*2*8192];

    const int tid  = threadIdx.x;
    const int lane = tid & 63, w = tid >> 6;
    const int l16  = lane & 15, quad = lane >> 4;
    const int wr   = w >> 2, wc = w & 3;

    // bijective XCD-aware block swizzle (all launches have nwg % 8 == 0)
    int nwg = gridDim.x * gridDim.y;
    int wg  = blockIdx.y * gridDim.x + blockIdx.x;
    if ((nwg & 7) == 0) wg = (wg & 7) * (nwg >> 3) + (wg >> 3);
    const int bn = wg % gridDim.x, bm = wg / gridDim.x;
    const int bz = blockIdx.z;
    const int kbeg = bz * klen;
    const int T = klen >> 6;

    const unsigned short* Abase = A  + (size_t)bm * 256 * K;
    const unsigned short* Bbase = Bt + (size_t)bn * 256 * K;

    // staging constants: 2 chunks/thread/half-tile; chunk c -> line c>>3, pos c&7 holds
    // global chunk (pos ^ line)&7 of row-pair line (rows 2L, 2L+1 x 32 K-elems).
    const int c0l = tid >> 3, c0q = tid & 7;
    const int sw0 = (c0q ^ c0l) & 7;
    const int aro0 = (2*c0l + (sw0 >> 2)) * K + (sw0 & 3) * 8;
    const int aro1 = aro0 + 128 * K;               // chunk c+512: line += 64, swizzle unchanged
    const int ld0  = tid * 8, ld1 = tid * 8 + 4096;

#define STG(_t, isB, kc) do{ \
    const unsigned short* gb = (isB) ? Bbase : Abase; \
    unsigned short* lb = ((isB) ? Bsl : Asl) + ((((_t)&1)<<1)|(kc))*8192; \
    const int ko = kbeg + (_t)*64 + (kc)*32; \
    gload_lds16(gb + aro0 + ko, lb + ld0); \
    gload_lds16(gb + aro1 + ko, lb + ld1); \
}while(0)

    // fragment read addresses: row r -> line r>>1, chunk q = (r&1)*4+quad, pos (q^L)&7.
    // pos's low-3-bit XOR is invariant across mi/nj (+8 lines) and the +32-line step,
    // so each (buffer, kc) needs ONE address VGPR; mi/nj walk via offset: immediates.
    const int qa  = ((l16 & 1) << 2) | quad;
    const int aL0 = wr*64 + (l16 >> 1);
    const int bL0 = wc*32 + (l16 >> 1);
    const unsigned Abase3 = ldsaddr(Asl) + (unsigned)(aL0*128 + ((qa ^ aL0) & 7)*16);
    const unsigned Bbase3 = ldsaddr(Bsl) + (unsigned)(bL0*128 + ((qa ^ bL0) & 7)*16);

#define MM16(MB) \
    _Pragma("unroll") \
    for (int mi = 0; mi < 4; ++mi){ \
      _Pragma("unroll") \
      for (int nj = 0; nj < 4; ++nj) \
        acc[(MB)+mi][nj] = __builtin_amdgcn_mfma_f32_16x16x32_bf16(af[mi], bf[nj], acc[(MB)+mi][nj], 0, 0, 0); \
    }

#define LGKM0() do{ \
    asm volatile("s_waitcnt lgkmcnt(0)" ::: "memory"); \
    __builtin_amdgcn_sched_barrier(0); \
}while(0)

    f32x4 acc[8][4] = {};

    // prologue: stage tile 0 fully, wait, barrier
    STG(0,0,0); STG(0,0,1); STG(0,1,0); STG(0,1,1);
    asm volatile("s_waitcnt vmcnt(0)" ::: "memory");
    __builtin_amdgcn_sched_barrier(0);
    __builtin_amdgcn_s_barrier();

    for (int t = 0; t < T; ++t){
        const unsigned sel = (t & 1) ? 32768u : 0u;
        const unsigned aA0 = Abase3 + sel, aA1 = aA0 + 16384u;
        const unsigned aB0 = Bbase3 + sel, aB1 = aB0 + 16384u;
        short8 af[4], bf[4];

        // stage ALL of tile t+1 into the opposite buffer (no hazard with tile t's reads)
        if (t + 1 < T){ STG(t+1,0,0); STG(t+1,0,1); STG(t+1,1,0); STG(t+1,1,1); }

        // ---- C1: kc0, mi 0-3 (8 ds_read)
        DSR(af[0], aA0, 0); DSR(af[1], aA0, 1024); DSR(af[2], aA0, 2048); DSR(af[3], aA0, 3072);
        DSR(bf[0], aB0, 0); DSR(bf[1], aB0, 1024); DSR(bf[2], aB0, 2048); DSR(bf[3], aB0, 3072);
        LGKM0();
        __builtin_amdgcn_s_setprio(1);
        MM16(0)
        __builtin_amdgcn_s_setprio(0);

        // ---- C2: kc0, mi 4-7 (4 ds_read, B reused)
        DSR(af[0], aA0, 4096); DSR(af[1], aA0, 5120); DSR(af[2], aA0, 6144); DSR(af[3], aA0, 7168);
        LGKM0();
        __builtin_amdgcn_s_setprio(1);
        MM16(4)
        __builtin_amdgcn_s_setprio(0);

        // ---- C3: kc1, mi 0-3 (8 ds_read)
        DSR(af[0], aA1, 0); DSR(af[1], aA1, 1024); DSR(af[2], aA1, 2048); DSR(af[3], aA1, 3072);
        DSR(bf[0], aB1, 0); DSR(bf[1], aB1, 1024); DSR(bf[2], aB1, 2048); DSR(bf[3], aB1, 3072);
        LGKM0();
        __builtin_amdgcn_s_setprio(1);
        MM16(0)
        __builtin_amdgcn_s_setprio(0);

        // ---- C4: kc1, mi 4-7 (4 ds_read)
        DSR(af[0], aA1, 4096); DSR(af[1], aA1, 5120); DSR(af[2], aA1, 6144); DSR(af[3], aA1, 7168);
        LGKM0();
        __builtin_amdgcn_s_setprio(1);
        MM16(4)
        __builtin_amdgcn_s_setprio(0);

        // ---- single sync point per tile: next tile's stage landed (issued a full
        // tile ago -> slack >> HBM latency), then all waves agree before buffer swap.
        asm volatile("s_waitcnt vmcnt(0)" ::: "memory");
        __builtin_amdgcn_sched_barrier(0);
        __builtin_amdgcn_s_barrier();
    }

#undef STG
#undef MM16
#undef LGKM0

    if (act == 2 && bn >= 6){
        // V cols: vtg[(b*H+h)*64 + d][s] with within-32 slot permutation
        // slot(k) = ((k>>2)&3)*8 + ((k>>4)&1)*4 + (k&3)
        #pragma unroll
        for (int mi = 0; mi < 8; ++mi){
            int rowbase = bm*256 + wr*128 + mi*16 + quad*4;
            int bidx = rowbase >> 11, s0 = rowbase & 2047;
            int sp = (s0 & ~31) | (((s0 >> 2) & 3) << 3) | (((s0 >> 4) & 1) << 2);
            #pragma unroll
            for (int nj = 0; nj < 4; ++nj){
                int col  = bn*256 + wc*64 + nj*16 + l16;
                int hcol = col - 2*D_;
                int hh   = hcol >> 6, dd = hcol & 63;
                float bia = bias ? bias[col] : 0.f;
                unsigned long long pk = 0;
                #pragma unroll
                for (int r = 0; r < 4; ++r)
                    pk |= (unsigned long long)f2b(acc[mi][nj][r] + bia) << (16*r);
                *(unsigned long long*)(vtg + (((size_t)bidx*H_ + hh)*64 + dd)*2048 + sp) = pk;
            }
        }
        return;
    }

    float* Cfz = Cf ? (Cf + (size_t)bz * M * N) : nullptr;
    const bool addb = (bias != nullptr) && (bz == 0);
    #pragma unroll
    for (int mi = 0; mi < 8; ++mi){
        #pragma unroll
        for (int nj = 0; nj < 4; ++nj){
            int col = bn*256 + wc*64 + nj*16 + l16;
            float bia = addb ? bias[col] : 0.f;
            #pragma unroll
            for (int r = 0; r < 4; ++r){
                int row = bm*256 + wr*128 + mi*16 + quad*4 + r;
                float v = acc[mi][nj][r] + bia;
                if (act == 1){
                    // tanh-GELU (max abs err ~3e-4, well within tolerance)
                    float u = v * (0.7978845608028654f + 0.0356774081f * v * v);
                    float e = __builtin_amdgcn_exp2f(u * 2.885390081777927f);  // e^(2u)
                    v = 0.5f * v * (1.f + (1.f - 2.f / (e + 1.f)));
                } else if (act == 2 && col < D_) v *= QSCALE;
                size_t idx = (size_t)row * N + col;
                if (Cfz) Cfz[idx] = v;
                if (Cb) Cb[idx] = f2b(v);
            }
        }
    }
}

// ---------------------------------------------------------------- attention
// S^T = K Q^T; P^T's C-layout regs ARE the PV A-fragment under key-permutation pi;
// V^T stored globally with pi pre-applied. No-max softmax (p = exp2(s) directly).
// 512 threads (8 waves x 16 q = 128 q/block), 128-key tiles, fused per-32-key
// granule S->exp->PV (minimal live VGPRs -> high occupancy + ILP across granules).
__global__ __launch_bounds__(512, 6) void attn_kernel(
    const unsigned short* __restrict__ qkv,
    const unsigned short* __restrict__ vtg,
    const int* __restrict__ mask,
    unsigned short* __restrict__ ctx)
{
    __shared__ __align__(16) unsigned short Kl[128*64];   // [key][dchunk ^ (key&7)]
    __shared__ __align__(16) unsigned short Vt[64*128];   // [d][slotchunk ^ (d&15)]

    const int tid = threadIdx.x;
    const int bid = blockIdx.x;                  // 768 = 48 heads * 16 qb
    const int hid = bid % 48;                    // same head -> same XCD (bid%8 fixed)
    const int qb  = bid / 48;
    const int h   = hid % H_;
    const int b   = hid / H_;
    const int w   = tid >> 6, lane = tid & 63;
    const int l16 = lane & 15, quad = lane >> 4;
    const int q0  = qb * 128 + w * 16;
    const size_t base = (size_t)b * S_;
    const int hoff = h * HD_;

    // Q as B-frag: n=q=lane&15, k-slot (quad,j) -> d = kc*32+quad*8+j
    short8 qf[2];
    #pragma unroll
    for (int kc = 0; kc < 2; ++kc)
        qf[kc] = *(const short8*)(qkv + (base + q0 + l16)*2304 + hoff + kc*32 + quad*8);

    f32x4 o[4] = {};
    float l_s = 0.f;

    const unsigned short* vrow = vtg + ((size_t)(b*H_ + h) * 64) * 2048;

    for (int kt = 0; kt < S_/128; ++kt){
        __syncthreads();
        #pragma unroll
        for (int c0 = 0; c0 < 2; ++c0){
            int c = tid + c0*512;                 // 1024 chunks each
            int rr = c >> 3, ch = c & 7;
            int sw = (ch ^ rr) & 7;
            gload_lds16(qkv + (base + kt*128 + rr)*2304 + D_ + hoff + sw*8, Kl + c*8);
            int d = c >> 4, pch = c & 15;
            int lch = (pch ^ d) & 15;
            gload_lds16(vrow + (size_t)d*2048 + kt*128 + lch*8, Vt + c*8);
        }
        __syncthreads();

        // mask fast-path flag (wave-uniform)
        int mv0 = mask[b*S_ + kt*128 + lane];
        int mv1 = mask[b*S_ + kt*128 + 64 + lane];
        const bool allok = __all((mv0 != 0) && (mv1 != 0));

        // 4 independent 32-key granules: S^T (2 tiles) -> exp2 -> pack -> PV
        #pragma unroll
        for (int t = 0; t < 4; ++t){
            f32x4 sf2[2] = {};
            #pragma unroll
            for (int kc = 0; kc < 2; ++kc){
                int co = (((kc*4 + quad) ^ l16) & 7)*8;
                short8 k0 = *(const short8*)&Kl[((2*t  )*16 + l16)*64 + co];
                short8 k1 = *(const short8*)&Kl[((2*t+1)*16 + l16)*64 + co];
                sf2[0] = __builtin_amdgcn_mfma_f32_16x16x32_bf16(k0, qf[kc], sf2[0], 0, 0, 0);
                sf2[1] = __builtin_amdgcn_mfma_f32_16x16x32_bf16(k1, qf[kc], sf2[1], 0, 0, 0);
            }
            if (!allok){
                #pragma unroll
                for (int j = 0; j < 2; ++j)
                    #pragma unroll
                    for (int r = 0; r < 4; ++r)
                        if (mask[b*S_ + kt*128 + (2*t+j)*16 + quad*4 + r] == 0)
                            sf2[j][r] = -1e30f;
            }
            #pragma unroll
            for (int j = 0; j < 2; ++j)
                #pragma unroll
                for (int r = 0; r < 4; ++r){
                    float p = __builtin_amdgcn_exp2f(sf2[j][r]);
                    sf2[j][r] = p; l_s += p;
                }
            union { unsigned int u[4]; short8 s; } pk;
            pk.u[0] = __builtin_amdgcn_perm(__float_as_uint(sf2[0][1]), __float_as_uint(sf2[0][0]), 0x07060302u);
            pk.u[1] = __builtin_amdgcn_perm(__float_as_uint(sf2[0][3]), __float_as_uint(sf2[0][2]), 0x07060302u);
            pk.u[2] = __builtin_amdgcn_perm(__float_as_uint(sf2[1][1]), __float_as_uint(sf2[1][0]), 0x07060302u);
            pk.u[3] = __builtin_amdgcn_perm(__float_as_uint(sf2[1][3]), __float_as_uint(sf2[1][2]), 0x07060302u);
            #pragma unroll
            for (int nt = 0; nt < 4; ++nt){
                int d = nt*16 + l16;
                short8 vf = *(const short8*)&Vt[d*128 + (((t*4 + quad) ^ l16) & 15)*8];
                o[nt] = __builtin_amdgcn_mfma_f32_16x16x32_bf16(pk.s, vf, o[nt], 0, 0, 0);
            }
        }
    }

    // reduce l across the 4 quad-copies of each column, normalize + write
    l_s += __shfl_xor(l_s, 16);
    l_s += __shfl_xor(l_s, 32);
    float linv[4];
    #pragma unroll
    for (int r = 0; r < 4; ++r)
        linv[r] = 1.f / __shfl(l_s, quad*4 + r);
    #pragma unroll
    for (int nt = 0; nt < 4; ++nt)
        #pragma unroll
        for (int r = 0; r < 4; ++r){
            int qrow = q0 + quad*4 + r;
            ctx[(base + qrow)*D_ + hoff + nt*16 + l16] = f2b(o[nt][r] * linv[r]);
        }
}

// ---------------------------------------------------------------- LayerNorm (+residual f32 or bf16, up to 2 partials)
__global__ __launch_bounds__(256) void ln_kernel(
    const float* __restrict__ inp, const float* __restrict__ inp2,
    const float* __restrict__ resf, const unsigned short* __restrict__ resb,
    const float* __restrict__ g, const float* __restrict__ be,
    float* __restrict__ outf, unsigned short* __restrict__ outb)
{
    const int row = blockIdx.x;
    const int tid = threadIdx.x;
    const float* ip = inp + (size_t)row * D_;
    const float* ip2 = inp2 ? inp2 + (size_t)row * D_ : nullptr;

    float v[3], s = 0.f, ss = 0.f;
    #pragma unroll
    for (int i = 0; i < 3; ++i){
        int c = tid + i*256;
        float x = ip[c];
        if (ip2) x += ip2[c];
        x += resf ? resf[(size_t)row * D_ + c] : b2f(resb[(size_t)row * D_ + c]);
        v[i] = x; s += x; ss += x * x;
    }
    #pragma unroll
    for (int d = 1; d < 64; d <<= 1){ s += __shfl_xor(s, d); ss += __shfl_xor(ss, d); }
    __shared__ float rs[4], rss[4];
    int w = tid >> 6;
    if ((tid & 63) == 0){ rs[w] = s; rss[w] = ss; }
    __syncthreads();
    s  = rs[0] + rs[1] + rs[2] + rs[3];
    ss = rss[0] + rss[1] + rss[2] + rss[3];
    float mu   = s * (1.f / 768.f);
    float var  = ss * (1.f / 768.f) - mu * mu;
    float rstd = rsqrtf(var + 1e-6f);
    #pragma unroll
    for (int i = 0; i < 3; ++i){
        int c = tid + i*256;
        float y = (v[i] - mu) * rstd * g[c] + be[c];
        if (outf) outf[(size_t)row * D_ + c] = y;
        if (outb) outb[(size_t)row * D_ + c] = f2b(y);
    }
}

// ---------------------------------------------------------------- launch
extern "C" void kernel_launch(void* const* d_in, const int* in_sizes, int n_in,
                              void* d_out, int out_size, void* d_ws, size_t ws_size,
                              hipStream_t stream)
{
    const float* x    = (const float*)d_in[0];
    const int*   mask = (const int*)  d_in[1];
    const float* Wq   = (const float*)d_in[2];
    const float* bq   = (const float*)d_in[3];
    const float* Wk   = (const float*)d_in[4];
    const float* bk   = (const float*)d_in[5];
    const float* Wv   = (const float*)d_in[6];
    const float* bv   = (const float*)d_in[7];
    const float* Wo   = (const float*)d_in[8];
    const float* bo   = (const float*)d_in[9];
    const float* W1   = (const float*)d_in[10];
    const float* b1   = (const float*)d_in[11];
    const float* W2   = (const float*)d_in[12];
    const float* b2   = (const float*)d_in[13];
    const float* g1   = (const float*)d_in[14];
    const float* be1  = (const float*)d_in[15];
    const float* g2   = (const float*)d_in[16];
    const float* be2  = (const float*)d_in[17];
    float* out = (float*)d_out;
    (void)in_sizes; (void)n_in; (void)out_size; (void)ws_size;

    char* ws = (char*)d_ws;
    const size_t n_x = (size_t)BS_ * D_;

    size_t off = 0;
    auto take = [&](size_t bytes){ size_t o = off; off += (bytes + 255) & ~(size_t)255; return o; };
    unsigned short* xb    = (unsigned short*)(ws + take(n_x * 2));   // dead after QKV; reused as hb
    unsigned short* hb    = xb;
    unsigned short* wqkvT = (unsigned short*)(ws + take((size_t)3*D_*D_ * 2));
    unsigned short* woT   = (unsigned short*)(ws + take((size_t)D_*D_ * 2));
    unsigned short* w1T   = (unsigned short*)(ws + take((size_t)D_*DF_ * 2));
    unsigned short* w2T   = (unsigned short*)(ws + take((size_t)D_*DF_ * 2));
    float*          bqkv  = (float*)(ws + take((size_t)3*D_ * 4));
    // qkv [BS][2304] + ctx [BS][768]; region reused by ff1 [BS][3072]
    size_t big = take((size_t)BS_ * 2304 * 2 + n_x * 2);
    unsigned short* qkvb = (unsigned short*)(ws + big);
    unsigned short* ctxb = qkvb + (size_t)BS_ * 2304;
    unsigned short* ff1b = qkvb;
    // fp32 partials (2x): Wo split-K partials, later FFN2 split-K partials
    float* pf32 = (float*)(ws + take(2 * n_x * 4));
    float* mhaf = pf32;
    float* ff2f = pf32;
    unsigned short* vtg = (unsigned short*)(ws + take(n_x * 2));   // [B*H][64][2048] bf16 (pi-permuted)

    // merged prep: cvt x + 6 weight transposes + bias concat in ONE launch
    prep_kernel<<<24576 + 3*2304 + 9, 256, 0, stream>>>(
        x, Wq, Wk, Wv, Wo, W1, W2, bq, bk, bv,
        xb, wqkvT, woT, w1T, w2T, bqkv);

    dim3 blk(512);
    // fused QKV projection: Q scaled, K normal -> qkvb; V -> vtg transposed+permuted
    gemm_tn<<<dim3(9, 32, 1), blk, 0, stream>>>(xb, wqkvT, bqkv, nullptr, qkvb, vtg, BS_, 3*D_, D_, D_, 2);
    // attention (512-thread blocks)
    attn_kernel<<<B_ * H_ * (S_/128), 512, 0, stream>>>(qkvb, vtg, mask, ctxb);
    // output projection -> fp32, split-K=2
    gemm_tn<<<dim3(3, 32, 2), blk, 0, stream>>>(ctxb, woT, bo, mhaf, nullptr, nullptr, BS_, D_, D_, D_/2, 0);
    // LN1 (two Wo partials + residual x) -> h bf16 only
    ln_kernel<<<BS_, 256, 0, stream>>>(mhaf, mhaf + n_x, x, nullptr, g1, be1, nullptr, hb);
    // FFN1 + tanh-GELU -> bf16
    gemm_tn<<<dim3(12, 32, 1), blk, 0, stream>>>(hb, w1T, b1, nullptr, ff1b, nullptr, BS_, DF_, D_, D_, 1);
    // FFN2 -> fp32, split-K=2
    gemm_tn<<<dim3(3, 32, 2), blk, 0, stream>>>(ff1b, w2T, b2, ff2f, nullptr, nullptr, BS_, D_, DF_, DF_/2, 0);
    // LN2 -> out (two partials + bf16 residual h)
    ln_kernel<<<BS_, 256, 0, stream>>>(ff2f, ff2f + n_x, nullptr, hb, g2, be2, out, nullptr);
}

// Round 5
// 403.622 us; speedup vs baseline: 1.1168x; 1.1168x over previous
//
#include <hip/hip_runtime.h>
#include <hip/hip_bf16.h>
#include <math.h>

#define B_  4
#define S_  2048
#define D_  768
#define H_  12
#define HD_ 64
#define DF_ 3072
#define BS_ (B_*S_)

// 0.125 (hd^-0.5) * log2(e): folded into Q projection so softmax runs in exp2 domain
#define QSCALE 0.18033688011112042f

typedef __attribute__((ext_vector_type(8))) short short8;
typedef __attribute__((ext_vector_type(4))) float f32x4;

__device__ __forceinline__ unsigned short f2b(float f){
    unsigned int x = __float_as_uint(f);
    return (unsigned short)((x + 0x7fffu + ((x >> 16) & 1u)) >> 16);   // RNE
}
__device__ __forceinline__ float b2f(unsigned short u){
    return __uint_as_float(((unsigned int)u) << 16);
}

typedef __attribute__((address_space(1))) void gvoid_t;
typedef __attribute__((address_space(3))) void lvoid_t;
__device__ __forceinline__ void gload_lds16(const unsigned short* g, unsigned short* l){
    __builtin_amdgcn_global_load_lds((gvoid_t*)g, (lvoid_t*)l, 16, 0, 0);
}

// ---------------------------------------------------------------- merged prep
// grid sections: [0,24576) cvt x | 4*576 DxD transposes | 2304 W1 | 2304 W2 | 9 bias
__global__ __launch_bounds__(256) void prep_kernel(
    const float* __restrict__ x,
    const float* __restrict__ Wq, const float* __restrict__ Wk,
    const float* __restrict__ Wv, const float* __restrict__ Wo,
    const float* __restrict__ W1, const float* __restrict__ W2,
    const float* __restrict__ bq, const float* __restrict__ bk, const float* __restrict__ bv,
    unsigned short* __restrict__ xb, unsigned short* __restrict__ wqkvT,
    unsigned short* __restrict__ woT, unsigned short* __restrict__ w1T,
    unsigned short* __restrict__ w2T, float* __restrict__ bqkv)
{
    const int NCVT = (BS_*D_)/256;         // 24576
    int bid = blockIdx.x;
    if (bid < NCVT){
        int i = bid*256 + threadIdx.x;
        xb[i] = f2b(x[i]);
        return;
    }
    bid -= NCVT;
    __shared__ float t[32][33];
    const float* src; unsigned short* dst; int K, N, bx, by;
    if (bid < 4*576){
        int wsel = bid / 576, tt = bid % 576;
        bx = tt % 24; by = tt / 24; K = D_; N = D_;
        src = (wsel==0)?Wq:(wsel==1)?Wk:(wsel==2)?Wv:Wo;
        dst = (wsel<3) ? (wqkvT + (size_t)wsel*D_*D_) : woT;
    } else if (bid < 4*576 + 2304){
        int tt = bid - 4*576; bx = tt % 96; by = tt / 96; K = D_; N = DF_; src = W1; dst = w1T;
    } else if (bid < 4*576 + 2*2304){
        int tt = bid - 4*576 - 2304; bx = tt % 24; by = tt / 24; K = DF_; N = D_; src = W2; dst = w2T;
    } else {
        int i = (bid - (4*576 + 2*2304))*256 + threadIdx.x;
        if (i < 3*D_) bqkv[i] = (i < D_) ? bq[i] : (i < 2*D_) ? bk[i-D_] : bv[i-2*D_];
        return;
    }
    int tx = threadIdx.x & 31, ty = threadIdx.x >> 5;
    #pragma unroll
    for (int i = 0; i < 4; ++i)
        t[ty + i*8][tx] = src[(size_t)(by*32 + ty + i*8) * N + bx*32 + tx];
    __syncthreads();
    #pragma unroll
    for (int i = 0; i < 4; ++i)
        dst[(size_t)(bx*32 + ty + i*8) * K + by*32 + tx] = f2b(t[tx][ty + i*8]);
}

// ---------------------------------------------------------------- GEMM (BK=64, swizzled)
// C[M,N] = A[M,K] @ Bt[N,K]^T + bias.  BM=BN=128, BK=64, 4 waves 2x2 of 64x64.
// Staging via global_load_lds w/ XOR chunk swizzle (contiguous LDS, conflict-free frags).
// act: 0 none, 1 tanh-GELU, 2 QKV-mode. split-K via blockIdx.z (klen per z).
// Round-5 deltas vs the proven 82.6µs/421µs version (A/B on the latency-bound theory):
//  (1) __launch_bounds__(256,4): LDS 32KB permits 5 blocks/CU; 60 VGPR + 64 acc = 124 <= 128
//      fits 4 waves/SIMD -> 16 waves/CU (was 3 blocks / 30% occupancy). Cross-BLOCK overlap is
//      the latency hider (m114): rounds 0/2/4 showed schedule shape is irrelevant at low TLP.
//  (2) bijective XCD swizzle: each XCD gets a contiguous tile range -> A-panel L2 locality (T1).
__global__ __launch_bounds__(256, 4) void gemm_tn(
    const unsigned short* __restrict__ A,
    const unsigned short* __restrict__ Bt,
    const float* __restrict__ bias,
    float* __restrict__ Cf,
    unsigned short* __restrict__ Cb,
    unsigned short* __restrict__ vtg,
    int M, int N, int K, int klen, int act)
{
    __shared__ __align__(16) unsigned short As[128*64];
    __shared__ __align__(16) unsigned short Bs[128*64];

    const int tid  = threadIdx.x;
    const int bz   = blockIdx.z;
    const int w    = tid >> 6, lane = tid & 63;
    const int l16  = lane & 15, quad = lane >> 4;
    const int wm   = (w >> 1) * 64, wn = (w & 1) * 64;
    const int kbeg = bz * klen;

    // bijective XCD-aware tile remap (all launches have nwg % 8 == 0):
    // XCD k owns tiles [k*nwg/8, (k+1)*nwg/8) -> contiguous bm rows per XCD L2.
    const int nwg = gridDim.x * gridDim.y;
    int wg = blockIdx.y * gridDim.x + blockIdx.x;
    wg = (wg & 7) * (nwg >> 3) + (wg >> 3);
    const int bn = wg % gridDim.x, bm = wg / gridDim.x;

    const unsigned short* Abase = A  + (size_t)bm * 128 * K;
    const unsigned short* Bbase = Bt + (size_t)bn * 128 * K;

    f32x4 acc[4][4] = {};

    for (int kt = kbeg; kt < kbeg + klen; kt += 64){
        #pragma unroll
        for (int c0 = 0; c0 < 4; ++c0){
            int c = tid + c0 * 256;                 // 1024 chunks of 16B per matrix
            int row = c >> 3, q = c & 7;
            int sw = (q ^ row) & 7;                 // chunk swizzle
            gload_lds16(Abase + (size_t)row * K + kt + sw*8, As + c*8);
            gload_lds16(Bbase + (size_t)row * K + kt + sw*8, Bs + c*8);
        }
        __syncthreads();

        #pragma unroll
        for (int kc = 0; kc < 2; ++kc){
            short8 af[4], bf[4];
            #pragma unroll
            for (int mi = 0; mi < 4; ++mi)
                af[mi] = *(const short8*)&As[(wm + mi*16 + l16)*64 + (((kc*4 + quad) ^ l16) & 7)*8];
            #pragma unroll
            for (int ni = 0; ni < 4; ++ni)
                bf[ni] = *(const short8*)&Bs[(wn + ni*16 + l16)*64 + (((kc*4 + quad) ^ l16) & 7)*8];
            #pragma unroll
            for (int mi = 0; mi < 4; ++mi)
                #pragma unroll
                for (int ni = 0; ni < 4; ++ni)
                    acc[mi][ni] = __builtin_amdgcn_mfma_f32_16x16x32_bf16(af[mi], bf[ni], acc[mi][ni], 0, 0, 0);
        }
        __syncthreads();
    }

    if (act == 2 && bn >= 12){
        // V cols: vtg[(b*H+h)*64 + d][s] with within-32 slot permutation
        // slot(k) = ((k>>2)&3)*8 + ((k>>4)&1)*4 + (k&3)
        #pragma unroll
        for (int mi = 0; mi < 4; ++mi){
            int rowbase = bm*128 + wm + mi*16 + quad*4;
            int bidx = rowbase >> 11, s0 = rowbase & 2047;
            int sp = (s0 & ~31) | (((s0 >> 2) & 3) << 3) | (((s0 >> 4) & 1) << 2);
            #pragma unroll
            for (int ni = 0; ni < 4; ++ni){
                int col  = bn*128 + wn + ni*16 + l16;
                int hcol = col - 2*D_;
                int hh   = hcol >> 6, dd = hcol & 63;
                float bia = bias ? bias[col] : 0.f;
                unsigned long long pk = 0;
                #pragma unroll
                for (int r = 0; r < 4; ++r)
                    pk |= (unsigned long long)f2b(acc[mi][ni][r] + bia) << (16*r);
                *(unsigned long long*)(vtg + (((size_t)bidx*H_ + hh)*64 + dd)*2048 + sp) = pk;
            }
        }
        return;
    }

    float* Cfz = Cf ? (Cf + (size_t)bz * M * N) : nullptr;
    const bool addb = (bias != nullptr) && (bz == 0);
    #pragma unroll
    for (int mi = 0; mi < 4; ++mi){
        #pragma unroll
        for (int ni = 0; ni < 4; ++ni){
            int col = bn*128 + wn + ni*16 + l16;
            float bia = addb ? bias[col] : 0.f;
            #pragma unroll
            for (int r = 0; r < 4; ++r){
                int row = bm*128 + wm + mi*16 + quad*4 + r;
                float v = acc[mi][ni][r] + bia;
                if (act == 1){
                    // tanh-GELU (max abs err ~3e-4, well within tolerance)
                    float u = v * (0.7978845608028654f + 0.0356774081f * v * v);
                    float e = __builtin_amdgcn_exp2f(u * 2.885390081777927f);  // e^(2u)
                    v = 0.5f * v * (1.f + (1.f - 2.f / (e + 1.f)));
                } else if (act == 2 && col < D_) v *= QSCALE;
                size_t idx = (size_t)row * N + col;
                if (Cfz) Cfz[idx] = v;
                if (Cb) Cb[idx] = f2b(v);
            }
        }
    }
}

// ---------------------------------------------------------------- attention
// S^T = K Q^T; P^T's C-layout regs ARE the PV A-fragment under key-permutation pi;
// V^T stored globally with pi pre-applied. No-max softmax (p = exp2(s) directly).
// 512 threads (8 waves x 16 q = 128 q/block), 128-key tiles, fused per-32-key
// granule S->exp->PV (minimal live VGPRs -> high occupancy + ILP across granules).
__global__ __launch_bounds__(512, 6) void attn_kernel(
    const unsigned short* __restrict__ qkv,
    const unsigned short* __restrict__ vtg,
    const int* __restrict__ mask,
    unsigned short* __restrict__ ctx)
{
    __shared__ __align__(16) unsigned short Kl[128*64];   // [key][dchunk ^ (key&7)]
    __shared__ __align__(16) unsigned short Vt[64*128];   // [d][slotchunk ^ (d&15)]

    const int tid = threadIdx.x;
    const int bid = blockIdx.x;                  // 768 = 48 heads * 16 qb
    const int hid = bid % 48;                    // same head -> same XCD (bid%8 fixed)
    const int qb  = bid / 48;
    const int h   = hid % H_;
    const int b   = hid / H_;
    const int w   = tid >> 6, lane = tid & 63;
    const int l16 = lane & 15, quad = lane >> 4;
    const int q0  = qb * 128 + w * 16;
    const size_t base = (size_t)b * S_;
    const int hoff = h * HD_;

    // Q as B-frag: n=q=lane&15, k-slot (quad,j) -> d = kc*32+quad*8+j
    short8 qf[2];
    #pragma unroll
    for (int kc = 0; kc < 2; ++kc)
        qf[kc] = *(const short8*)(qkv + (base + q0 + l16)*2304 + hoff + kc*32 + quad*8);

    f32x4 o[4] = {};
    float l_s = 0.f;

    const unsigned short* vrow = vtg + ((size_t)(b*H_ + h) * 64) * 2048;

    for (int kt = 0; kt < S_/128; ++kt){
        __syncthreads();
        #pragma unroll
        for (int c0 = 0; c0 < 2; ++c0){
            int c = tid + c0*512;                 // 1024 chunks each
            int rr = c >> 3, ch = c & 7;
            int sw = (ch ^ rr) & 7;
            gload_lds16(qkv + (base + kt*128 + rr)*2304 + D_ + hoff + sw*8, Kl + c*8);
            int d = c >> 4, pch = c & 15;
            int lch = (pch ^ d) & 15;
            gload_lds16(vrow + (size_t)d*2048 + kt*128 + lch*8, Vt + c*8);
        }
        __syncthreads();

        // mask fast-path flag (wave-uniform)
        int mv0 = mask[b*S_ + kt*128 + lane];
        int mv1 = mask[b*S_ + kt*128 + 64 + lane];
        const bool allok = __all((mv0 != 0) && (mv1 != 0));

        // 4 independent 32-key granules: S^T (2 tiles) -> exp2 -> pack -> PV
        #pragma unroll
        for (int t = 0; t < 4; ++t){
            f32x4 sf2[2] = {};
            #pragma unroll
            for (int kc = 0; kc < 2; ++kc){
                int co = (((kc*4 + quad) ^ l16) & 7)*8;
                short8 k0 = *(const short8*)&Kl[((2*t  )*16 + l16)*64 + co];
                short8 k1 = *(const short8*)&Kl[((2*t+1)*16 + l16)*64 + co];
                sf2[0] = __builtin_amdgcn_mfma_f32_16x16x32_bf16(k0, qf[kc], sf2[0], 0, 0, 0);
                sf2[1] = __builtin_amdgcn_mfma_f32_16x16x32_bf16(k1, qf[kc], sf2[1], 0, 0, 0);
            }
            if (!allok){
                #pragma unroll
                for (int j = 0; j < 2; ++j)
                    #pragma unroll
                    for (int r = 0; r < 4; ++r)
                        if (mask[b*S_ + kt*128 + (2*t+j)*16 + quad*4 + r] == 0)
                            sf2[j][r] = -1e30f;
            }
            #pragma unroll
            for (int j = 0; j < 2; ++j)
                #pragma unroll
                for (int r = 0; r < 4; ++r){
                    float p = __builtin_amdgcn_exp2f(sf2[j][r]);
                    sf2[j][r] = p; l_s += p;
                }
            union { unsigned int u[4]; short8 s; } pk;
            pk.u[0] = __builtin_amdgcn_perm(__float_as_uint(sf2[0][1]), __float_as_uint(sf2[0][0]), 0x07060302u);
            pk.u[1] = __builtin_amdgcn_perm(__float_as_uint(sf2[0][3]), __float_as_uint(sf2[0][2]), 0x07060302u);
            pk.u[2] = __builtin_amdgcn_perm(__float_as_uint(sf2[1][1]), __float_as_uint(sf2[1][0]), 0x07060302u);
            pk.u[3] = __builtin_amdgcn_perm(__float_as_uint(sf2[1][3]), __float_as_uint(sf2[1][2]), 0x07060302u);
            #pragma unroll
            for (int nt = 0; nt < 4; ++nt){
                int d = nt*16 + l16;
                short8 vf = *(const short8*)&Vt[d*128 + (((t*4 + quad) ^ l16) & 15)*8];
                o[nt] = __builtin_amdgcn_mfma_f32_16x16x32_bf16(pk.s, vf, o[nt], 0, 0, 0);
            }
        }
    }

    // reduce l across the 4 quad-copies of each column, normalize + write
    l_s += __shfl_xor(l_s, 16);
    l_s += __shfl_xor(l_s, 32);
    float linv[4];
    #pragma unroll
    for (int r = 0; r < 4; ++r)
        linv[r] = 1.f / __shfl(l_s, quad*4 + r);
    #pragma unroll
    for (int nt = 0; nt < 4; ++nt)
        #pragma unroll
        for (int r = 0; r < 4; ++r){
            int qrow = q0 + quad*4 + r;
            ctx[(base + qrow)*D_ + hoff + nt*16 + l16] = f2b(o[nt][r] * linv[r]);
        }
}

// ---------------------------------------------------------------- LayerNorm (+residual f32 or bf16, up to 2 partials)
__global__ __launch_bounds__(256) void ln_kernel(
    const float* __restrict__ inp, const float* __restrict__ inp2,
    const float* __restrict__ resf, const unsigned short* __restrict__ resb,
    const float* __restrict__ g, const float* __restrict__ be,
    float* __restrict__ outf, unsigned short* __restrict__ outb)
{
    const int row = blockIdx.x;
    const int tid = threadIdx.x;
    const float* ip = inp + (size_t)row * D_;
    const float* ip2 = inp2 ? inp2 + (size_t)row * D_ : nullptr;

    float v[3], s = 0.f, ss = 0.f;
    #pragma unroll
    for (int i = 0; i < 3; ++i){
        int c = tid + i*256;
        float x = ip[c];
        if (ip2) x += ip2[c];
        x += resf ? resf[(size_t)row * D_ + c] : b2f(resb[(size_t)row * D_ + c]);
        v[i] = x; s += x; ss += x * x;
    }
    #pragma unroll
    for (int d = 1; d < 64; d <<= 1){ s += __shfl_xor(s, d); ss += __shfl_xor(ss, d); }
    __shared__ float rs[4], rss[4];
    int w = tid >> 6;
    if ((tid & 63) == 0){ rs[w] = s; rss[w] = ss; }
    __syncthreads();
    s  = rs[0] + rs[1] + rs[2] + rs[3];
    ss = rss[0] + rss[1] + rss[2] + rss[3];
    float mu   = s * (1.f / 768.f);
    float var  = ss * (1.f / 768.f) - mu * mu;
    float rstd = rsqrtf(var + 1e-6f);
    #pragma unroll
    for (int i = 0; i < 3; ++i){
        int c = tid + i*256;
        float y = (v[i] - mu) * rstd * g[c] + be[c];
        if (outf) outf[(size_t)row * D_ + c] = y;
        if (outb) outb[(size_t)row * D_ + c] = f2b(y);
    }
}

// ---------------------------------------------------------------- launch
extern "C" void kernel_launch(void* const* d_in, const int* in_sizes, int n_in,
                              void* d_out, int out_size, void* d_ws, size_t ws_size,
                              hipStream_t stream)
{
    const float* x    = (const float*)d_in[0];
    const int*   mask = (const int*)  d_in[1];
    const float* Wq   = (const float*)d_in[2];
    const float* bq   = (const float*)d_in[3];
    const float* Wk   = (const float*)d_in[4];
    const float* bk   = (const float*)d_in[5];
    const float* Wv   = (const float*)d_in[6];
    const float* bv   = (const float*)d_in[7];
    const float* Wo   = (const float*)d_in[8];
    const float* bo   = (const float*)d_in[9];
    const float* W1   = (const float*)d_in[10];
    const float* b1   = (const float*)d_in[11];
    const float* W2   = (const float*)d_in[12];
    const float* b2   = (const float*)d_in[13];
    const float* g1   = (const float*)d_in[14];
    const float* be1  = (const float*)d_in[15];
    const float* g2   = (const float*)d_in[16];
    const float* be2  = (const float*)d_in[17];
    float* out = (float*)d_out;
    (void)in_sizes; (void)n_in; (void)out_size; (void)ws_size;

    char* ws = (char*)d_ws;
    const size_t n_x = (size_t)BS_ * D_;

    size_t off = 0;
    auto take = [&](size_t bytes){ size_t o = off; off += (bytes + 255) & ~(size_t)255; return o; };
    unsigned short* xb    = (unsigned short*)(ws + take(n_x * 2));   // dead after QKV; reused as hb
    unsigned short* hb    = xb;
    unsigned short* wqkvT = (unsigned short*)(ws + take((size_t)3*D_*D_ * 2));
    unsigned short* woT   = (unsigned short*)(ws + take((size_t)D_*D_ * 2));
    unsigned short* w1T   = (unsigned short*)(ws + take((size_t)D_*DF_ * 2));
    unsigned short* w2T   = (unsigned short*)(ws + take((size_t)D_*DF_ * 2));
    float*          bqkv  = (float*)(ws + take((size_t)3*D_ * 4));
    // qkv [BS][2304] + ctx [BS][768]; region reused by ff1 [BS][3072]
    size_t big = take((size_t)BS_ * 2304 * 2 + n_x * 2);
    unsigned short* qkvb = (unsigned short*)(ws + big);
    unsigned short* ctxb = qkvb + (size_t)BS_ * 2304;
    unsigned short* ff1b = qkvb;
    // fp32 partials (2x): Wo split-K partials, later FFN2 split-K partials
    float* pf32 = (float*)(ws + take(2 * n_x * 4));
    float* mhaf = pf32;
    float* ff2f = pf32;
    unsigned short* vtg = (unsigned short*)(ws + take(n_x * 2));   // [B*H][64][2048] bf16 (pi-permuted)

    // merged prep: cvt x + 6 weight transposes + bias concat in ONE launch
    prep_kernel<<<24576 + 3*2304 + 9, 256, 0, stream>>>(
        x, Wq, Wk, Wv, Wo, W1, W2, bq, bk, bv,
        xb, wqkvT, woT, w1T, w2T, bqkv);

    dim3 blk(256);
    // fused QKV projection: Q scaled, K normal -> qkvb; V -> vtg transposed+permuted
    gemm_tn<<<dim3(18, 64, 1), blk, 0, stream>>>(xb, wqkvT, bqkv, nullptr, qkvb, vtg, BS_, 3*D_, D_, D_, 2);
    // attention (512-thread blocks)
    attn_kernel<<<B_ * H_ * (S_/128), 512, 0, stream>>>(qkvb, vtg, mask, ctxb);
    // output projection -> fp32, split-K=2
    gemm_tn<<<dim3(6, 64, 2), blk, 0, stream>>>(ctxb, woT, bo, mhaf, nullptr, nullptr, BS_, D_, D_, D_/2, 0);
    // LN1 (two Wo partials + residual x) -> h bf16 only
    ln_kernel<<<BS_, blk, 0, stream>>>(mhaf, mhaf + n_x, x, nullptr, g1, be1, nullptr, hb);
    // FFN1 + tanh-GELU -> bf16
    gemm_tn<<<dim3(24, 64, 1), blk, 0, stream>>>(hb, w1T, b1, nullptr, ff1b, nullptr, BS_, DF_, D_, D_, 1);
    // FFN2 -> fp32, split-K=2
    gemm_tn<<<dim3(6, 64, 2), blk, 0, stream>>>(ff1b, w2T, b2, ff2f, nullptr, nullptr, BS_, D_, DF_, DF_/2, 0);
    // LN2 -> out (two partials + bf16 residual h)
    ln_kernel<<<BS_, blk, 0, stream>>>(ff2f, ff2f + n_x, nullptr, hb, g2, be2, out, nullptr);
}

// Round 6
// 389.566 us; speedup vs baseline: 1.1570x; 1.0361x over previous
//
#include <hip/hip_runtime.h>
#include <hip/hip_bf16.h>
#include <math.h>

#define B_  4
#define S_  2048
#define D_  768
#define H_  12
#define HD_ 64
#define DF_ 3072
#define BS_ (B_*S_)

// 0.125 (hd^-0.5) * log2(e): folded into Q projection so softmax runs in exp2 domain
#define QSCALE 0.18033688011112042f

typedef __attribute__((ext_vector_type(8))) short short8;
typedef __attribute__((ext_vector_type(4))) float f32x4;

__device__ __forceinline__ unsigned short f2b(float f){
    unsigned int x = __float_as_uint(f);
    return (unsigned short)((x + 0x7fffu + ((x >> 16) & 1u)) >> 16);   // RNE
}
__device__ __forceinline__ float b2f(unsigned short u){
    return __uint_as_float(((unsigned int)u) << 16);
}

typedef __attribute__((address_space(1))) void gvoid_t;
typedef __attribute__((address_space(3))) void lvoid_t;
__device__ __forceinline__ void gload_lds16(const unsigned short* g, unsigned short* l){
    __builtin_amdgcn_global_load_lds((gvoid_t*)g, (lvoid_t*)l, 16, 0, 0);
}

// ---------------------------------------------------------------- merged prep
// grid sections: [0,24576) cvt x | 4*576 DxD transposes | 2304 W1 | 2304 W2 | 9 bias
__global__ __launch_bounds__(256) void prep_kernel(
    const float* __restrict__ x,
    const float* __restrict__ Wq, const float* __restrict__ Wk,
    const float* __restrict__ Wv, const float* __restrict__ Wo,
    const float* __restrict__ W1, const float* __restrict__ W2,
    const float* __restrict__ bq, const float* __restrict__ bk, const float* __restrict__ bv,
    unsigned short* __restrict__ xb, unsigned short* __restrict__ wqkvT,
    unsigned short* __restrict__ woT, unsigned short* __restrict__ w1T,
    unsigned short* __restrict__ w2T, float* __restrict__ bqkv)
{
    const int NCVT = (BS_*D_)/256;         // 24576
    int bid = blockIdx.x;
    if (bid < NCVT){
        int i = bid*256 + threadIdx.x;
        xb[i] = f2b(x[i]);
        return;
    }
    bid -= NCVT;
    __shared__ float t[32][33];
    const float* src; unsigned short* dst; int K, N, bx, by;
    if (bid < 4*576){
        int wsel = bid / 576, tt = bid % 576;
        bx = tt % 24; by = tt / 24; K = D_; N = D_;
        src = (wsel==0)?Wq:(wsel==1)?Wk:(wsel==2)?Wv:Wo;
        dst = (wsel<3) ? (wqkvT + (size_t)wsel*D_*D_) : woT;
    } else if (bid < 4*576 + 2304){
        int tt = bid - 4*576; bx = tt % 96; by = tt / 96; K = D_; N = DF_; src = W1; dst = w1T;
    } else if (bid < 4*576 + 2*2304){
        int tt = bid - 4*576 - 2304; bx = tt % 24; by = tt / 24; K = DF_; N = D_; src = W2; dst = w2T;
    } else {
        int i = (bid - (4*576 + 2*2304))*256 + threadIdx.x;
        if (i < 3*D_) bqkv[i] = (i < D_) ? bq[i] : (i < 2*D_) ? bk[i-D_] : bv[i-2*D_];
        return;
    }
    int tx = threadIdx.x & 31, ty = threadIdx.x >> 5;
    #pragma unroll
    for (int i = 0; i < 4; ++i)
        t[ty + i*8][tx] = src[(size_t)(by*32 + ty + i*8) * N + bx*32 + tx];
    __syncthreads();
    #pragma unroll
    for (int i = 0; i < 4; ++i)
        dst[(size_t)(bx*32 + ty + i*8) * K + by*32 + tx] = f2b(t[tx][ty + i*8]);
}

// ---------------------------------------------------------------- GEMM (BK=64, swizzled)
// C[M,N] = A[M,K] @ Bt[N,K]^T + bias.  BM=BN=128, BK=64, 4 waves 2x2 of 64x64.
// Staging via global_load_lds w/ XOR chunk swizzle (contiguous LDS, conflict-free frags).
// act: 0 none, 1 tanh-GELU, 2 QKV-mode. split-K via blockIdx.z (klen per z).
//  (1) __launch_bounds__(256,4): 16 waves/CU — cross-BLOCK overlap is the latency hider
//      (rounds 0/2/4 A/B: schedule shape was irrelevant at low TLP; occupancy was the lever).
//  (2) bijective XCD swizzle: contiguous tile range per XCD -> A-panel L2 locality (T1).
__global__ __launch_bounds__(256, 4) void gemm_tn(
    const unsigned short* __restrict__ A,
    const unsigned short* __restrict__ Bt,
    const float* __restrict__ bias,
    float* __restrict__ Cf,
    unsigned short* __restrict__ Cb,
    unsigned short* __restrict__ vtg,
    int M, int N, int K, int klen, int act)
{
    __shared__ __align__(16) unsigned short As[128*64];
    __shared__ __align__(16) unsigned short Bs[128*64];

    const int tid  = threadIdx.x;
    const int bz   = blockIdx.z;
    const int w    = tid >> 6, lane = tid & 63;
    const int l16  = lane & 15, quad = lane >> 4;
    const int wm   = (w >> 1) * 64, wn = (w & 1) * 64;
    const int kbeg = bz * klen;

    // bijective XCD-aware tile remap (all launches have nwg % 8 == 0):
    // XCD k owns tiles [k*nwg/8, (k+1)*nwg/8) -> contiguous bm rows per XCD L2.
    const int nwg = gridDim.x * gridDim.y;
    int wg = blockIdx.y * gridDim.x + blockIdx.x;
    wg = (wg & 7) * (nwg >> 3) + (wg >> 3);
    const int bn = wg % gridDim.x, bm = wg / gridDim.x;

    const unsigned short* Abase = A  + (size_t)bm * 128 * K;
    const unsigned short* Bbase = Bt + (size_t)bn * 128 * K;

    f32x4 acc[4][4] = {};

    for (int kt = kbeg; kt < kbeg + klen; kt += 64){
        #pragma unroll
        for (int c0 = 0; c0 < 4; ++c0){
            int c = tid + c0 * 256;                 // 1024 chunks of 16B per matrix
            int row = c >> 3, q = c & 7;
            int sw = (q ^ row) & 7;                 // chunk swizzle
            gload_lds16(Abase + (size_t)row * K + kt + sw*8, As + c*8);
            gload_lds16(Bbase + (size_t)row * K + kt + sw*8, Bs + c*8);
        }
        __syncthreads();

        #pragma unroll
        for (int kc = 0; kc < 2; ++kc){
            short8 af[4], bf[4];
            #pragma unroll
            for (int mi = 0; mi < 4; ++mi)
                af[mi] = *(const short8*)&As[(wm + mi*16 + l16)*64 + (((kc*4 + quad) ^ l16) & 7)*8];
            #pragma unroll
            for (int ni = 0; ni < 4; ++ni)
                bf[ni] = *(const short8*)&Bs[(wn + ni*16 + l16)*64 + (((kc*4 + quad) ^ l16) & 7)*8];
            #pragma unroll
            for (int mi = 0; mi < 4; ++mi)
                #pragma unroll
                for (int ni = 0; ni < 4; ++ni)
                    acc[mi][ni] = __builtin_amdgcn_mfma_f32_16x16x32_bf16(af[mi], bf[ni], acc[mi][ni], 0, 0, 0);
        }
        __syncthreads();
    }

    if (act == 2 && bn >= 12){
        // V cols: vtg[(b*H+h)*64 + d][s] with within-32 slot permutation
        // slot(k) = ((k>>2)&3)*8 + ((k>>4)&1)*4 + (k&3)
        #pragma unroll
        for (int mi = 0; mi < 4; ++mi){
            int rowbase = bm*128 + wm + mi*16 + quad*4;
            int bidx = rowbase >> 11, s0 = rowbase & 2047;
            int sp = (s0 & ~31) | (((s0 >> 2) & 3) << 3) | (((s0 >> 4) & 1) << 2);
            #pragma unroll
            for (int ni = 0; ni < 4; ++ni){
                int col  = bn*128 + wn + ni*16 + l16;
                int hcol = col - 2*D_;
                int hh   = hcol >> 6, dd = hcol & 63;
                float bia = bias ? bias[col] : 0.f;
                unsigned long long pk = 0;
                #pragma unroll
                for (int r = 0; r < 4; ++r)
                    pk |= (unsigned long long)f2b(acc[mi][ni][r] + bia) << (16*r);
                *(unsigned long long*)(vtg + (((size_t)bidx*H_ + hh)*64 + dd)*2048 + sp) = pk;
            }
        }
        return;
    }

    float* Cfz = Cf ? (Cf + (size_t)bz * M * N) : nullptr;
    const bool addb = (bias != nullptr) && (bz == 0);
    #pragma unroll
    for (int mi = 0; mi < 4; ++mi){
        #pragma unroll
        for (int ni = 0; ni < 4; ++ni){
            int col = bn*128 + wn + ni*16 + l16;
            float bia = addb ? bias[col] : 0.f;
            #pragma unroll
            for (int r = 0; r < 4; ++r){
                int row = bm*128 + wm + mi*16 + quad*4 + r;
                float v = acc[mi][ni][r] + bia;
                if (act == 1){
                    // tanh-GELU (max abs err ~3e-4, well within tolerance)
                    float u = v * (0.7978845608028654f + 0.0356774081f * v * v);
                    float e = __builtin_amdgcn_exp2f(u * 2.885390081777927f);  // e^(2u)
                    v = 0.5f * v * (1.f + (1.f - 2.f / (e + 1.f)));
                } else if (act == 2 && col < D_) v *= QSCALE;
                size_t idx = (size_t)row * N + col;
                if (Cfz) Cfz[idx] = v;
                if (Cb) Cb[idx] = f2b(v);
            }
        }
    }
}

// ---------------------------------------------------------------- attention
// S^T = K Q^T; P^T's C-layout regs ARE the PV A-fragment under key-permutation pi;
// V^T stored globally with pi pre-applied. No-max softmax (p = exp2(s) directly).
// Round-6 restructure: attn was LDS-BW bound (per-CU ds_read_b128 time ~61µs of 71µs;
// every wave re-read full K/V tiles to serve only 16 q). Now 4 waves x 32 q each
// (2 q-GROUPS of 16): K-frags loaded ONCE per granule feed both groups' QK^T, each
// V-frag feeds both groups' PV -> LDS reads per q-row HALVED. Same math per q
// (bitwise-identical output); block still covers 128 q; grid unchanged (768, 3/CU).
__global__ __launch_bounds__(256, 3) void attn_kernel(
    const unsigned short* __restrict__ qkv,
    const unsigned short* __restrict__ vtg,
    const int* __restrict__ mask,
    unsigned short* __restrict__ ctx)
{
    __shared__ __align__(16) unsigned short Kl[128*64];   // [key][dchunk ^ (key&7)]
    __shared__ __align__(16) unsigned short Vt[64*128];   // [d][slotchunk ^ (d&15)]

    const int tid = threadIdx.x;
    const int bid = blockIdx.x;                  // 768 = 48 heads * 16 qb
    const int hid = bid % 48;                    // same head -> same XCD (bid%8 fixed)
    const int qb  = bid / 48;
    const int h   = hid % H_;
    const int b   = hid / H_;
    const int w   = tid >> 6, lane = tid & 63;   // w in 0..3
    const int l16 = lane & 15, quad = lane >> 4;
    const int q0  = qb * 128 + w * 32;           // wave owns 32 q rows = 2 groups of 16
    const size_t base = (size_t)b * S_;
    const int hoff = h * HD_;

    // Q as B-frag per group: n=q=lane&15, k-slot (quad,j) -> d = kc*32+quad*8+j
    short8 qf[2][2];
    #pragma unroll
    for (int g = 0; g < 2; ++g)
        #pragma unroll
        for (int kc = 0; kc < 2; ++kc)
            qf[g][kc] = *(const short8*)(qkv + (base + q0 + g*16 + l16)*2304 + hoff + kc*32 + quad*8);

    f32x4 o[2][4] = {};
    float l_s[2] = {0.f, 0.f};

    const unsigned short* vrow = vtg + ((size_t)(b*H_ + h) * 64) * 2048;

    for (int kt = 0; kt < S_/128; ++kt){
        __syncthreads();
        #pragma unroll
        for (int c0 = 0; c0 < 4; ++c0){
            int c = tid + c0*256;                 // 1024 chunks each
            int rr = c >> 3, ch = c & 7;
            int sw = (ch ^ rr) & 7;
            gload_lds16(qkv + (base + kt*128 + rr)*2304 + D_ + hoff + sw*8, Kl + c*8);
            int d = c >> 4, pch = c & 15;
            int lch = (pch ^ d) & 15;
            gload_lds16(vrow + (size_t)d*2048 + kt*128 + lch*8, Vt + c*8);
        }
        __syncthreads();

        // mask fast-path flag (wave-uniform)
        int mv0 = mask[b*S_ + kt*128 + lane];
        int mv1 = mask[b*S_ + kt*128 + 64 + lane];
        const bool allok = __all((mv0 != 0) && (mv1 != 0));

        // 4 independent 32-key granules: K-frags once -> both groups' S^T -> exp2 ->
        // pack -> shared-V PV for both groups
        #pragma unroll
        for (int t = 0; t < 4; ++t){
            short8 kf[2][2];
            #pragma unroll
            for (int kc = 0; kc < 2; ++kc){
                int co = (((kc*4 + quad) ^ l16) & 7)*8;
                kf[kc][0] = *(const short8*)&Kl[((2*t  )*16 + l16)*64 + co];
                kf[kc][1] = *(const short8*)&Kl[((2*t+1)*16 + l16)*64 + co];
            }
            short8 pks[2];
            #pragma unroll
            for (int g = 0; g < 2; ++g){
                f32x4 sf2[2] = {};
                #pragma unroll
                for (int kc = 0; kc < 2; ++kc){
                    sf2[0] = __builtin_amdgcn_mfma_f32_16x16x32_bf16(kf[kc][0], qf[g][kc], sf2[0], 0, 0, 0);
                    sf2[1] = __builtin_amdgcn_mfma_f32_16x16x32_bf16(kf[kc][1], qf[g][kc], sf2[1], 0, 0, 0);
                }
                if (!allok){
                    #pragma unroll
                    for (int j = 0; j < 2; ++j)
                        #pragma unroll
                        for (int r = 0; r < 4; ++r)
                            if (mask[b*S_ + kt*128 + (2*t+j)*16 + quad*4 + r] == 0)
                                sf2[j][r] = -1e30f;
                }
                #pragma unroll
                for (int j = 0; j < 2; ++j)
                    #pragma unroll
                    for (int r = 0; r < 4; ++r){
                        float p = __builtin_amdgcn_exp2f(sf2[j][r]);
                        sf2[j][r] = p; l_s[g] += p;
                    }
                union { unsigned int u[4]; short8 s; } pk;
                pk.u[0] = __builtin_amdgcn_perm(__float_as_uint(sf2[0][1]), __float_as_uint(sf2[0][0]), 0x07060302u);
                pk.u[1] = __builtin_amdgcn_perm(__float_as_uint(sf2[0][3]), __float_as_uint(sf2[0][2]), 0x07060302u);
                pk.u[2] = __builtin_amdgcn_perm(__float_as_uint(sf2[1][1]), __float_as_uint(sf2[1][0]), 0x07060302u);
                pk.u[3] = __builtin_amdgcn_perm(__float_as_uint(sf2[1][3]), __float_as_uint(sf2[1][2]), 0x07060302u);
                pks[g] = pk.s;
            }
            #pragma unroll
            for (int nt = 0; nt < 4; ++nt){
                int d = nt*16 + l16;
                short8 vf = *(const short8*)&Vt[d*128 + (((t*4 + quad) ^ l16) & 15)*8];
                o[0][nt] = __builtin_amdgcn_mfma_f32_16x16x32_bf16(pks[0], vf, o[0][nt], 0, 0, 0);
                o[1][nt] = __builtin_amdgcn_mfma_f32_16x16x32_bf16(pks[1], vf, o[1][nt], 0, 0, 0);
            }
        }
    }

    // per group: reduce l across the 4 quad-copies of each column, normalize + write
    #pragma unroll
    for (int g = 0; g < 2; ++g){
        float ls = l_s[g];
        ls += __shfl_xor(ls, 16);
        ls += __shfl_xor(ls, 32);
        float linv[4];
        #pragma unroll
        for (int r = 0; r < 4; ++r)
            linv[r] = 1.f / __shfl(ls, quad*4 + r);
        #pragma unroll
        for (int nt = 0; nt < 4; ++nt)
            #pragma unroll
            for (int r = 0; r < 4; ++r){
                int qrow = q0 + g*16 + quad*4 + r;
                ctx[(base + qrow)*D_ + hoff + nt*16 + l16] = f2b(o[g][nt][r] * linv[r]);
            }
    }
}

// ---------------------------------------------------------------- LayerNorm (+residual f32 or bf16, up to 2 partials)
__global__ __launch_bounds__(256) void ln_kernel(
    const float* __restrict__ inp, const float* __restrict__ inp2,
    const float* __restrict__ resf, const unsigned short* __restrict__ resb,
    const float* __restrict__ g, const float* __restrict__ be,
    float* __restrict__ outf, unsigned short* __restrict__ outb)
{
    const int row = blockIdx.x;
    const int tid = threadIdx.x;
    const float* ip = inp + (size_t)row * D_;
    const float* ip2 = inp2 ? inp2 + (size_t)row * D_ : nullptr;

    float v[3], s = 0.f, ss = 0.f;
    #pragma unroll
    for (int i = 0; i < 3; ++i){
        int c = tid + i*256;
        float x = ip[c];
        if (ip2) x += ip2[c];
        x += resf ? resf[(size_t)row * D_ + c] : b2f(resb[(size_t)row * D_ + c]);
        v[i] = x; s += x; ss += x * x;
    }
    #pragma unroll
    for (int d = 1; d < 64; d <<= 1){ s += __shfl_xor(s, d); ss += __shfl_xor(ss, d); }
    __shared__ float rs[4], rss[4];
    int w = tid >> 6;
    if ((tid & 63) == 0){ rs[w] = s; rss[w] = ss; }
    __syncthreads();
    s  = rs[0] + rs[1] + rs[2] + rs[3];
    ss = rss[0] + rss[1] + rss[2] + rss[3];
    float mu   = s * (1.f / 768.f);
    float var  = ss * (1.f / 768.f) - mu * mu;
    float rstd = rsqrtf(var + 1e-6f);
    #pragma unroll
    for (int i = 0; i < 3; ++i){
        int c = tid + i*256;
        float y = (v[i] - mu) * rstd * g[c] + be[c];
        if (outf) outf[(size_t)row * D_ + c] = y;
        if (outb) outb[(size_t)row * D_ + c] = f2b(y);
    }
}

// ---------------------------------------------------------------- launch
extern "C" void kernel_launch(void* const* d_in, const int* in_sizes, int n_in,
                              void* d_out, int out_size, void* d_ws, size_t ws_size,
                              hipStream_t stream)
{
    const float* x    = (const float*)d_in[0];
    const int*   mask = (const int*)  d_in[1];
    const float* Wq   = (const float*)d_in[2];
    const float* bq   = (const float*)d_in[3];
    const float* Wk   = (const float*)d_in[4];
    const float* bk   = (const float*)d_in[5];
    const float* Wv   = (const float*)d_in[6];
    const float* bv   = (const float*)d_in[7];
    const float* Wo   = (const float*)d_in[8];
    const float* bo   = (const float*)d_in[9];
    const float* W1   = (const float*)d_in[10];
    const float* b1   = (const float*)d_in[11];
    const float* W2   = (const float*)d_in[12];
    const float* b2   = (const float*)d_in[13];
    const float* g1   = (const float*)d_in[14];
    const float* be1  = (const float*)d_in[15];
    const float* g2   = (const float*)d_in[16];
    const float* be2  = (const float*)d_in[17];
    float* out = (float*)d_out;
    (void)in_sizes; (void)n_in; (void)out_size; (void)ws_size;

    char* ws = (char*)d_ws;
    const size_t n_x = (size_t)BS_ * D_;

    size_t off = 0;
    auto take = [&](size_t bytes){ size_t o = off; off += (bytes + 255) & ~(size_t)255; return o; };
    unsigned short* xb    = (unsigned short*)(ws + take(n_x * 2));   // dead after QKV; reused as hb
    unsigned short* hb    = xb;
    unsigned short* wqkvT = (unsigned short*)(ws + take((size_t)3*D_*D_ * 2));
    unsigned short* woT   = (unsigned short*)(ws + take((size_t)D_*D_ * 2));
    unsigned short* w1T   = (unsigned short*)(ws + take((size_t)D_*DF_ * 2));
    unsigned short* w2T   = (unsigned short*)(ws + take((size_t)D_*DF_ * 2));
    float*          bqkv  = (float*)(ws + take((size_t)3*D_ * 4));
    // qkv [BS][2304] + ctx [BS][768]; region reused by ff1 [BS][3072]
    size_t big = take((size_t)BS_ * 2304 * 2 + n_x * 2);
    unsigned short* qkvb = (unsigned short*)(ws + big);
    unsigned short* ctxb = qkvb + (size_t)BS_ * 2304;
    unsigned short* ff1b = qkvb;
    // fp32 partials (2x): Wo split-K partials, later FFN2 split-K partials
    float* pf32 = (float*)(ws + take(2 * n_x * 4));
    float* mhaf = pf32;
    float* ff2f = pf32;
    unsigned short* vtg = (unsigned short*)(ws + take(n_x * 2));   // [B*H][64][2048] bf16 (pi-permuted)

    // merged prep: cvt x + 6 weight transposes + bias concat in ONE launch
    prep_kernel<<<24576 + 3*2304 + 9, 256, 0, stream>>>(
        x, Wq, Wk, Wv, Wo, W1, W2, bq, bk, bv,
        xb, wqkvT, woT, w1T, w2T, bqkv);

    dim3 blk(256);
    // fused QKV projection: Q scaled, K normal -> qkvb; V -> vtg transposed+permuted
    gemm_tn<<<dim3(18, 64, 1), blk, 0, stream>>>(xb, wqkvT, bqkv, nullptr, qkvb, vtg, BS_, 3*D_, D_, D_, 2);
    // attention (256-thread blocks, 4 waves x 32 q)
    attn_kernel<<<B_ * H_ * (S_/128), 256, 0, stream>>>(qkvb, vtg, mask, ctxb);
    // output projection -> fp32, split-K=2
    gemm_tn<<<dim3(6, 64, 2), blk, 0, stream>>>(ctxb, woT, bo, mhaf, nullptr, nullptr, BS_, D_, D_, D_/2, 0);
    // LN1 (two Wo partials + residual x) -> h bf16 only
    ln_kernel<<<BS_, blk, 0, stream>>>(mhaf, mhaf + n_x, x, nullptr, g1, be1, nullptr, hb);
    // FFN1 + tanh-GELU -> bf16
    gemm_tn<<<dim3(24, 64, 1), blk, 0, stream>>>(hb, w1T, b1, nullptr, ff1b, nullptr, BS_, DF_, D_, D_, 1);
    // FFN2 -> fp32, split-K=2
    gemm_tn<<<dim3(6, 64, 2), blk, 0, stream>>>(ff1b, w2T, b2, ff2f, nullptr, nullptr, BS_, D_, DF_, DF_/2, 0);
    // LN2 -> out (two partials + bf16 residual h)
    ln_kernel<<<BS_, blk, 0, stream>>>(ff2f, ff2f + n_x, nullptr, hb, g2, be2, out, nullptr);
}

// Round 7
// 389.501 us; speedup vs baseline: 1.1572x; 1.0002x over previous
//
#include <hip/hip_runtime.h>
#include <hip/hip_bf16.h>
#include <math.h>

#define B_  4
#define S_  2048
#define D_  768
#define H_  12
#define HD_ 64
#define DF_ 3072
#define BS_ (B_*S_)

// 0.125 (hd^-0.5) * log2(e): folded into Q projection so softmax runs in exp2 domain
#define QSCALE 0.18033688011112042f

typedef __attribute__((ext_vector_type(8))) short short8;
typedef __attribute__((ext_vector_type(4))) float f32x4;

__device__ __forceinline__ unsigned short f2b(float f){
    unsigned int x = __float_as_uint(f);
    return (unsigned short)((x + 0x7fffu + ((x >> 16) & 1u)) >> 16);   // RNE
}
__device__ __forceinline__ float b2f(unsigned short u){
    return __uint_as_float(((unsigned int)u) << 16);
}

typedef __attribute__((address_space(1))) void gvoid_t;
typedef __attribute__((address_space(3))) void lvoid_t;
typedef __attribute__((address_space(3))) unsigned char lchar_t;
__device__ __forceinline__ void gload_lds16(const unsigned short* g, unsigned short* l){
    __builtin_amdgcn_global_load_lds((gvoid_t*)g, (lvoid_t*)l, 16, 0, 0);
}
__device__ __forceinline__ unsigned ldsaddr(const void* p){
    return (unsigned)(size_t)(lchar_t*)(lvoid_t*)p;
}
// inline-asm ds_read_b128: bypasses compiler alias analysis so NO conservative
// vmcnt(0) drains get inserted against outstanding global_load_lds (rule #18 —
// must pair with explicit lgkmcnt + sched_barrier(0) before the consuming MFMA).
#define DSR(dst, addr, OFF) \
    asm volatile("ds_read_b128 %0, %1 offset:" #OFF : "=v"(dst) : "v"(addr))

// ---------------------------------------------------------------- merged prep
// grid sections: [0,24576) cvt x | 4*576 DxD transposes | 2304 W1 | 2304 W2 | 9 bias
__global__ __launch_bounds__(256) void prep_kernel(
    const float* __restrict__ x,
    const float* __restrict__ Wq, const float* __restrict__ Wk,
    const float* __restrict__ Wv, const float* __restrict__ Wo,
    const float* __restrict__ W1, const float* __restrict__ W2,
    const float* __restrict__ bq, const float* __restrict__ bk, const float* __restrict__ bv,
    unsigned short* __restrict__ xb, unsigned short* __restrict__ wqkvT,
    unsigned short* __restrict__ woT, unsigned short* __restrict__ w1T,
    unsigned short* __restrict__ w2T, float* __restrict__ bqkv)
{
    const int NCVT = (BS_*D_)/256;         // 24576
    int bid = blockIdx.x;
    if (bid < NCVT){
        int i = bid*256 + threadIdx.x;
        xb[i] = f2b(x[i]);
        return;
    }
    bid -= NCVT;
    __shared__ float t[32][33];
    const float* src; unsigned short* dst; int K, N, bx, by;
    if (bid < 4*576){
        int wsel = bid / 576, tt = bid % 576;
        bx = tt % 24; by = tt / 24; K = D_; N = D_;
        src = (wsel==0)?Wq:(wsel==1)?Wk:(wsel==2)?Wv:Wo;
        dst = (wsel<3) ? (wqkvT + (size_t)wsel*D_*D_) : woT;
    } else if (bid < 4*576 + 2304){
        int tt = bid - 4*576; bx = tt % 96; by = tt / 96; K = D_; N = DF_; src = W1; dst = w1T;
    } else if (bid < 4*576 + 2*2304){
        int tt = bid - 4*576 - 2304; bx = tt % 24; by = tt / 24; K = DF_; N = D_; src = W2; dst = w2T;
    } else {
        int i = (bid - (4*576 + 2*2304))*256 + threadIdx.x;
        if (i < 3*D_) bqkv[i] = (i < D_) ? bq[i] : (i < 2*D_) ? bk[i-D_] : bv[i-2*D_];
        return;
    }
    int tx = threadIdx.x & 31, ty = threadIdx.x >> 5;
    #pragma unroll
    for (int i = 0; i < 4; ++i)
        t[ty + i*8][tx] = src[(size_t)(by*32 + ty + i*8) * N + bx*32 + tx];
    __syncthreads();
    #pragma unroll
    for (int i = 0; i < 4; ++i)
        dst[(size_t)(bx*32 + ty + i*8) * K + by*32 + tx] = f2b(t[tx][ty + i*8]);
}

// ---------------------------------------------------------------- GEMM (BK=64, swizzled)
// C[M,N] = A[M,K] @ Bt[N,K]^T + bias.  BM=BN=128, BK=64, 4 waves 2x2 of 64x64.
// Staging via global_load_lds w/ XOR chunk swizzle (contiguous LDS, conflict-free frags).
// act: 0 none, 1 tanh-GELU, 2 QKV-mode. split-K via blockIdx.z (klen per z).
//  (1) __launch_bounds__(256,4): 16 waves/CU — cross-BLOCK overlap is the latency hider
//      (rounds 0/2/4 A/B: schedule shape was irrelevant at low TLP; occupancy was the lever).
//  (2) bijective XCD swizzle: contiguous tile range per XCD -> A-panel L2 locality (T1).
__global__ __launch_bounds__(256, 4) void gemm_tn(
    const unsigned short* __restrict__ A,
    const unsigned short* __restrict__ Bt,
    const float* __restrict__ bias,
    float* __restrict__ Cf,
    unsigned short* __restrict__ Cb,
    unsigned short* __restrict__ vtg,
    int M, int N, int K, int klen, int act)
{
    __shared__ __align__(16) unsigned short As[128*64];
    __shared__ __align__(16) unsigned short Bs[128*64];

    const int tid  = threadIdx.x;
    const int bz   = blockIdx.z;
    const int w    = tid >> 6, lane = tid & 63;
    const int l16  = lane & 15, quad = lane >> 4;
    const int wm   = (w >> 1) * 64, wn = (w & 1) * 64;
    const int kbeg = bz * klen;

    // bijective XCD-aware tile remap (all launches have nwg % 8 == 0):
    // XCD k owns tiles [k*nwg/8, (k+1)*nwg/8) -> contiguous bm rows per XCD L2.
    const int nwg = gridDim.x * gridDim.y;
    int wg = blockIdx.y * gridDim.x + blockIdx.x;
    wg = (wg & 7) * (nwg >> 3) + (wg >> 3);
    const int bn = wg % gridDim.x, bm = wg / gridDim.x;

    const unsigned short* Abase = A  + (size_t)bm * 128 * K;
    const unsigned short* Bbase = Bt + (size_t)bn * 128 * K;

    f32x4 acc[4][4] = {};

    for (int kt = kbeg; kt < kbeg + klen; kt += 64){
        #pragma unroll
        for (int c0 = 0; c0 < 4; ++c0){
            int c = tid + c0 * 256;                 // 1024 chunks of 16B per matrix
            int row = c >> 3, q = c & 7;
            int sw = (q ^ row) & 7;                 // chunk swizzle
            gload_lds16(Abase + (size_t)row * K + kt + sw*8, As + c*8);
            gload_lds16(Bbase + (size_t)row * K + kt + sw*8, Bs + c*8);
        }
        __syncthreads();

        #pragma unroll
        for (int kc = 0; kc < 2; ++kc){
            short8 af[4], bf[4];
            #pragma unroll
            for (int mi = 0; mi < 4; ++mi)
                af[mi] = *(const short8*)&As[(wm + mi*16 + l16)*64 + (((kc*4 + quad) ^ l16) & 7)*8];
            #pragma unroll
            for (int ni = 0; ni < 4; ++ni)
                bf[ni] = *(const short8*)&Bs[(wn + ni*16 + l16)*64 + (((kc*4 + quad) ^ l16) & 7)*8];
            #pragma unroll
            for (int mi = 0; mi < 4; ++mi)
                #pragma unroll
                for (int ni = 0; ni < 4; ++ni)
                    acc[mi][ni] = __builtin_amdgcn_mfma_f32_16x16x32_bf16(af[mi], bf[ni], acc[mi][ni], 0, 0, 0);
        }
        __syncthreads();
    }

    if (act == 2 && bn >= 12){
        // V cols: vtg[(b*H+h)*64 + d][s] with within-32 slot permutation
        // slot(k) = ((k>>2)&3)*8 + ((k>>4)&1)*4 + (k&3)
        #pragma unroll
        for (int mi = 0; mi < 4; ++mi){
            int rowbase = bm*128 + wm + mi*16 + quad*4;
            int bidx = rowbase >> 11, s0 = rowbase & 2047;
            int sp = (s0 & ~31) | (((s0 >> 2) & 3) << 3) | (((s0 >> 4) & 1) << 2);
            #pragma unroll
            for (int ni = 0; ni < 4; ++ni){
                int col  = bn*128 + wn + ni*16 + l16;
                int hcol = col - 2*D_;
                int hh   = hcol >> 6, dd = hcol & 63;
                float bia = bias ? bias[col] : 0.f;
                unsigned long long pk = 0;
                #pragma unroll
                for (int r = 0; r < 4; ++r)
                    pk |= (unsigned long long)f2b(acc[mi][ni][r] + bia) << (16*r);
                *(unsigned long long*)(vtg + (((size_t)bidx*H_ + hh)*64 + dd)*2048 + sp) = pk;
            }
        }
        return;
    }

    float* Cfz = Cf ? (Cf + (size_t)bz * M * N) : nullptr;
    const bool addb = (bias != nullptr) && (bz == 0);
    #pragma unroll
    for (int mi = 0; mi < 4; ++mi){
        #pragma unroll
        for (int ni = 0; ni < 4; ++ni){
            int col = bn*128 + wn + ni*16 + l16;
            float bia = addb ? bias[col] : 0.f;
            #pragma unroll
            for (int r = 0; r < 4; ++r){
                int row = bm*128 + wm + mi*16 + quad*4 + r;
                float v = acc[mi][ni][r] + bia;
                if (act == 1){
                    // tanh-GELU (max abs err ~3e-4, well within tolerance)
                    float u = v * (0.7978845608028654f + 0.0356774081f * v * v);
                    float e = __builtin_amdgcn_exp2f(u * 2.885390081777927f);  // e^(2u)
                    v = 0.5f * v * (1.f + (1.f - 2.f / (e + 1.f)));
                } else if (act == 2 && col < D_) v *= QSCALE;
                size_t idx = (size_t)row * N + col;
                if (Cfz) Cfz[idx] = v;
                if (Cb) Cb[idx] = f2b(v);
            }
        }
    }
}

// ---------------------------------------------------------------- attention
// S^T = K Q^T; P^T's C-layout regs ARE the PV A-fragment under key-permutation pi;
// V^T stored globally with pi pre-applied. No-max softmax (p = exp2(s) directly).
// 4 waves x 32 q (2 groups of 16); K-frags/V-frags loaded once per granule feed both
// groups (round-6 LDS-traffic halving, kept).
// Round-7: 64-key tiles, DOUBLE-BUFFERED LDS (2 x (8KB K + 8KB V) = 32KB, still 3
// blocks/CU): stage kt+1 at the top of kt's compute, single vmcnt(0)+barrier at tile
// end (slack = full tile of MFMA+VALU >> HBM latency) -> removes the 16 staging
// convoys that serialized LDS/VALU/MFMA pipes (round-6: 3 pipes x ~25-30us each but
// 60us wall). Fragment loads are inline-asm ds_read_b128 + counted lgkmcnt +
// sched_barrier(0) (rule #18) so the compiler inserts no alias-driven vmcnt drains.
// Mask fast-path bits hoisted to a prologue bitmask -> zero global reads in the
// steady-state loop. Key/MFMA/accumulation order identical -> bitwise-same output.
__global__ __launch_bounds__(256, 3) void attn_kernel(
    const unsigned short* __restrict__ qkv,
    const unsigned short* __restrict__ vtg,
    const int* __restrict__ mask,
    unsigned short* __restrict__ ctx)
{
    __shared__ __align__(16) unsigned short Kl[2*4096];   // [buf][key 0..63][dchunk ^ (key&7)]
    __shared__ __align__(16) unsigned short Vt[2*4096];   // [buf][d 0..63][slotchunk ^ (d&7)]

    const int tid = threadIdx.x;
    const int bid = blockIdx.x;                  // 768 = 48 heads * 16 qb
    const int hid = bid % 48;                    // same head -> same XCD (bid%8 fixed)
    const int qb  = bid / 48;
    const int h   = hid % H_;
    const int b   = hid / H_;
    const int w   = tid >> 6, lane = tid & 63;   // w in 0..3
    const int l16 = lane & 15, quad = lane >> 4;
    const int q0  = qb * 128 + w * 32;           // wave owns 32 q rows = 2 groups of 16
    const size_t base = (size_t)b * S_;
    const int hoff = h * HD_;

    // Q as B-frag per group: n=q=lane&15, k-slot (quad,j) -> d = kc*32+quad*8+j
    short8 qf[2][2];
    #pragma unroll
    for (int g = 0; g < 2; ++g)
        #pragma unroll
        for (int kc = 0; kc < 2; ++kc)
            qf[g][kc] = *(const short8*)(qkv + (base + q0 + g*16 + l16)*2304 + hoff + kc*32 + quad*8);

    // hoisted mask fast-path bits: bit kt = all 64 keys of tile kt unmasked.
    // Keeps the steady-state loop free of global reads (compiler would otherwise
    // insert vmcnt waits that drain the staging queue).
    unsigned okbits = 0;
    for (int kt = 0; kt < 32; ++kt){
        int mv = mask[b*S_ + kt*64 + lane];
        okbits |= (__all(mv != 0) ? (1u << kt) : 0u);
    }

    const unsigned short* vrow = vtg + ((size_t)(b*H_ + h) * 64) * 2048;

    // staging constants: 512 K-chunks + 512 V-chunks of 16B per tile, 4/thread.
    // K chunk c: row rr=c>>3 (key), LDS slot c&7 holds global chunk ((c&7)^rr)&7.
    // V chunk c: row d=c>>3, same XOR. cB = c+256: row += 32 -> swizzle unchanged (32&7==0).
    const int rrA  = tid >> 3, slA = tid & 7, swA = (slA ^ rrA) & 7;
    const int koffA = rrA*2304 + hoff + swA*8;           // + kq base (already includes D_)
    const int voffA = rrA*2048 + swA*8;
    unsigned short* kd = Kl + tid*8;
    unsigned short* vd = Vt + tid*8;

#define STAGE(_kt, _buf) do{ \
    const unsigned short* kq = qkv + (base + (size_t)(_kt)*64)*2304 + D_; \
    const unsigned short* vq = vrow + (_kt)*64; \
    gload_lds16(kq + koffA,           kd + (_buf)*4096); \
    gload_lds16(kq + koffA + 32*2304, kd + (_buf)*4096 + 2048); \
    gload_lds16(vq + voffA,           vd + (_buf)*4096); \
    gload_lds16(vq + voffA + 32*2048, vd + (_buf)*4096 + 2048); \
}while(0)

    // fragment read bases (byte addrs). K row (2t+j)*16+l16, chunk (kc*4+quad)^l16:
    //   byte = l16*128 + ((quad^l16)&7)*16 + (2t+j)*2048, kc=1 flips chunk bit2 -> ^64.
    // V row nt*16+l16, chunk (t*4+quad)^l16: byte = l16*128 + ((quad^l16)&7)*16 + nt*2048, t=1 -> ^64.
    const unsigned fb = (unsigned)(l16*128 + ((quad ^ l16) & 7)*16);
    const unsigned kr0 = ldsaddr(Kl) + fb, kr1 = kr0 ^ 64u;
    const unsigned vr0 = ldsaddr(Vt) + fb, vr1 = vr0 ^ 64u;

    f32x4 o[2][4] = {};
    float l_s[2] = {0.f, 0.f};

    // prologue: tile 0 into buf 0 (also drains Q/mask loads), barrier
    STAGE(0, 0);
    asm volatile("s_waitcnt vmcnt(0)" ::: "memory");
    __builtin_amdgcn_sched_barrier(0);
    __builtin_amdgcn_s_barrier();

    for (int kt = 0; kt < 32; ++kt){
        if (kt + 1 < 32) STAGE(kt + 1, (kt & 1) ^ 1);
        const unsigned rb = (unsigned)(kt & 1) << 13;   // read-buffer byte offset
        const bool allok = (okbits >> kt) & 1u;

        // 2 granules of 32 keys: K+V asm ds_reads -> lgkmcnt(4) (K ready) ->
        // QK^T both groups -> exp2/pack -> lgkmcnt(0) (V ready) -> PV both groups.
        #pragma unroll
        for (int t = 0; t < 2; ++t){
            const unsigned ka0 = kr0 + rb + t*4096, ka1 = kr1 + rb + t*4096;
            const unsigned va  = (t ? vr1 : vr0) + rb;
            short8 kf00, kf01, kf10, kf11, vf[4];
            DSR(kf00, ka0, 0); DSR(kf01, ka0, 2048);
            DSR(kf10, ka1, 0); DSR(kf11, ka1, 2048);
            DSR(vf[0], va, 0); DSR(vf[1], va, 2048); DSR(vf[2], va, 4096); DSR(vf[3], va, 6144);
            asm volatile("s_waitcnt lgkmcnt(4)" ::: "memory");
            __builtin_amdgcn_sched_barrier(0);

            short8 pks[2];
            #pragma unroll
            for (int g = 0; g < 2; ++g){
                f32x4 sf2[2] = {};
                sf2[0] = __builtin_amdgcn_mfma_f32_16x16x32_bf16(kf00, qf[g][0], sf2[0], 0, 0, 0);
                sf2[1] = __builtin_amdgcn_mfma_f32_16x16x32_bf16(kf01, qf[g][0], sf2[1], 0, 0, 0);
                sf2[0] = __builtin_amdgcn_mfma_f32_16x16x32_bf16(kf10, qf[g][1], sf2[0], 0, 0, 0);
                sf2[1] = __builtin_amdgcn_mfma_f32_16x16x32_bf16(kf11, qf[g][1], sf2[1], 0, 0, 0);
                if (!allok){
                    #pragma unroll
                    for (int j = 0; j < 2; ++j)
                        #pragma unroll
                        for (int r = 0; r < 4; ++r)
                            if (mask[b*S_ + kt*64 + (2*t+j)*16 + quad*4 + r] == 0)
                                sf2[j][r] = -1e30f;
                }
                #pragma unroll
                for (int j = 0; j < 2; ++j)
                    #pragma unroll
                    for (int r = 0; r < 4; ++r){
                        float p = __builtin_amdgcn_exp2f(sf2[j][r]);
                        sf2[j][r] = p; l_s[g] += p;
                    }
                union { unsigned int u[4]; short8 s; } pk;
                pk.u[0] = __builtin_amdgcn_perm(__float_as_uint(sf2[0][1]), __float_as_uint(sf2[0][0]), 0x07060302u);
                pk.u[1] = __builtin_amdgcn_perm(__float_as_uint(sf2[0][3]), __float_as_uint(sf2[0][2]), 0x07060302u);
                pk.u[2] = __builtin_amdgcn_perm(__float_as_uint(sf2[1][1]), __float_as_uint(sf2[1][0]), 0x07060302u);
                pk.u[3] = __builtin_amdgcn_perm(__float_as_uint(sf2[1][3]), __float_as_uint(sf2[1][2]), 0x07060302u);
                pks[g] = pk.s;
            }
            asm volatile("s_waitcnt lgkmcnt(0)" ::: "memory");
            __builtin_amdgcn_sched_barrier(0);
            #pragma unroll
            for (int nt = 0; nt < 4; ++nt){
                o[0][nt] = __builtin_amdgcn_mfma_f32_16x16x32_bf16(pks[0], vf[nt], o[0][nt], 0, 0, 0);
                o[1][nt] = __builtin_amdgcn_mfma_f32_16x16x32_bf16(pks[1], vf[nt], o[1][nt], 0, 0, 0);
            }
        }

        // single sync point per tile: my stage loads landed (issued a full tile ago),
        // all waves done reading the buffer that kt+2 will overwrite.
        asm volatile("s_waitcnt vmcnt(0)" ::: "memory");
        __builtin_amdgcn_sched_barrier(0);
        __builtin_amdgcn_s_barrier();
    }
#undef STAGE

    // per group: reduce l across the 4 quad-copies of each column, normalize + write
    #pragma unroll
    for (int g = 0; g < 2; ++g){
        float ls = l_s[g];
        ls += __shfl_xor(ls, 16);
        ls += __shfl_xor(ls, 32);
        float linv[4];
        #pragma unroll
        for (int r = 0; r < 4; ++r)
            linv[r] = 1.f / __shfl(ls, quad*4 + r);
        #pragma unroll
        for (int nt = 0; nt < 4; ++nt)
            #pragma unroll
            for (int r = 0; r < 4; ++r){
                int qrow = q0 + g*16 + quad*4 + r;
                ctx[(base + qrow)*D_ + hoff + nt*16 + l16] = f2b(o[g][nt][r] * linv[r]);
            }
    }
}

// ---------------------------------------------------------------- LayerNorm (+residual f32 or bf16, up to 2 partials)
__global__ __launch_bounds__(256) void ln_kernel(
    const float* __restrict__ inp, const float* __restrict__ inp2,
    const float* __restrict__ resf, const unsigned short* __restrict__ resb,
    const float* __restrict__ g, const float* __restrict__ be,
    float* __restrict__ outf, unsigned short* __restrict__ outb)
{
    const int row = blockIdx.x;
    const int tid = threadIdx.x;
    const float* ip = inp + (size_t)row * D_;
    const float* ip2 = inp2 ? inp2 + (size_t)row * D_ : nullptr;

    float v[3], s = 0.f, ss = 0.f;
    #pragma unroll
    for (int i = 0; i < 3; ++i){
        int c = tid + i*256;
        float x = ip[c];
        if (ip2) x += ip2[c];
        x += resf ? resf[(size_t)row * D_ + c] : b2f(resb[(size_t)row * D_ + c]);
        v[i] = x; s += x; ss += x * x;
    }
    #pragma unroll
    for (int d = 1; d < 64; d <<= 1){ s += __shfl_xor(s, d); ss += __shfl_xor(ss, d); }
    __shared__ float rs[4], rss[4];
    int w = tid >> 6;
    if ((tid & 63) == 0){ rs[w] = s; rss[w] = ss; }
    __syncthreads();
    s  = rs[0] + rs[1] + rs[2] + rs[3];
    ss = rss[0] + rss[1] + rss[2] + rss[3];
    float mu   = s * (1.f / 768.f);
    float var  = ss * (1.f / 768.f) - mu * mu;
    float rstd = rsqrtf(var + 1e-6f);
    #pragma unroll
    for (int i = 0; i < 3; ++i){
        int c = tid + i*256;
        float y = (v[i] - mu) * rstd * g[c] + be[c];
        if (outf) outf[(size_t)row * D_ + c] = y;
        if (outb) outb[(size_t)row * D_ + c] = f2b(y);
    }
}

// ---------------------------------------------------------------- launch
extern "C" void kernel_launch(void* const* d_in, const int* in_sizes, int n_in,
                              void* d_out, int out_size, void* d_ws, size_t ws_size,
                              hipStream_t stream)
{
    const float* x    = (const float*)d_in[0];
    const int*   mask = (const int*)  d_in[1];
    const float* Wq   = (const float*)d_in[2];
    const float* bq   = (const float*)d_in[3];
    const float* Wk   = (const float*)d_in[4];
    const float* bk   = (const float*)d_in[5];
    const float* Wv   = (const float*)d_in[6];
    const float* bv   = (const float*)d_in[7];
    const float* Wo   = (const float*)d_in[8];
    const float* bo   = (const float*)d_in[9];
    const float* W1   = (const float*)d_in[10];
    const float* b1   = (const float*)d_in[11];
    const float* W2   = (const float*)d_in[12];
    const float* b2   = (const float*)d_in[13];
    const float* g1   = (const float*)d_in[14];
    const float* be1  = (const float*)d_in[15];
    const float* g2   = (const float*)d_in[16];
    const float* be2  = (const float*)d_in[17];
    float* out = (float*)d_out;
    (void)in_sizes; (void)n_in; (void)out_size; (void)ws_size;

    char* ws = (char*)d_ws;
    const size_t n_x = (size_t)BS_ * D_;

    size_t off = 0;
    auto take = [&](size_t bytes){ size_t o = off; off += (bytes + 255) & ~(size_t)255; return o; };
    unsigned short* xb    = (unsigned short*)(ws + take(n_x * 2));   // dead after QKV; reused as hb
    unsigned short* hb    = xb;
    unsigned short* wqkvT = (unsigned short*)(ws + take((size_t)3*D_*D_ * 2));
    unsigned short* woT   = (unsigned short*)(ws + take((size_t)D_*D_ * 2));
    unsigned short* w1T   = (unsigned short*)(ws + take((size_t)D_*DF_ * 2));
    unsigned short* w2T   = (unsigned short*)(ws + take((size_t)D_*DF_ * 2));
    float*          bqkv  = (float*)(ws + take((size_t)3*D_ * 4));
    // qkv [BS][2304] + ctx [BS][768]; region reused by ff1 [BS][3072]
    size_t big = take((size_t)BS_ * 2304 * 2 + n_x * 2);
    unsigned short* qkvb = (unsigned short*)(ws + big);
    unsigned short* ctxb = qkvb + (size_t)BS_ * 2304;
    unsigned short* ff1b = qkvb;
    // fp32 partials (2x): Wo split-K partials, later FFN2 split-K partials
    float* pf32 = (float*)(ws + take(2 * n_x * 4));
    float* mhaf = pf32;
    float* ff2f = pf32;
    unsigned short* vtg = (unsigned short*)(ws + take(n_x * 2));   // [B*H][64][2048] bf16 (pi-permuted)

    // merged prep: cvt x + 6 weight transposes + bias concat in ONE launch
    prep_kernel<<<24576 + 3*2304 + 9, 256, 0, stream>>>(
        x, Wq, Wk, Wv, Wo, W1, W2, bq, bk, bv,
        xb, wqkvT, woT, w1T, w2T, bqkv);

    dim3 blk(256);
    // fused QKV projection: Q scaled, K normal -> qkvb; V -> vtg transposed+permuted
    gemm_tn<<<dim3(18, 64, 1), blk, 0, stream>>>(xb, wqkvT, bqkv, nullptr, qkvb, vtg, BS_, 3*D_, D_, D_, 2);
    // attention (256-thread blocks, 4 waves x 32 q, dbuf 64-key tiles)
    attn_kernel<<<B_ * H_ * (S_/128), 256, 0, stream>>>(qkvb, vtg, mask, ctxb);
    // output projection -> fp32, split-K=2
    gemm_tn<<<dim3(6, 64, 2), blk, 0, stream>>>(ctxb, woT, bo, mhaf, nullptr, nullptr, BS_, D_, D_, D_/2, 0);
    // LN1 (two Wo partials + residual x) -> h bf16 only
    ln_kernel<<<BS_, blk, 0, stream>>>(mhaf, mhaf + n_x, x, nullptr, g1, be1, nullptr, hb);
    // FFN1 + tanh-GELU -> bf16
    gemm_tn<<<dim3(24, 64, 1), blk, 0, stream>>>(hb, w1T, b1, nullptr, ff1b, nullptr, BS_, DF_, D_, D_, 1);
    // FFN2 -> fp32, split-K=2
    gemm_tn<<<dim3(6, 64, 2), blk, 0, stream>>>(ff1b, w2T, b2, ff2f, nullptr, nullptr, BS_, D_, DF_, DF_/2, 0);
    // LN2 -> out (two partials + bf16 residual h)
    ln_kernel<<<BS_, blk, 0, stream>>>(ff2f, ff2f + n_x, nullptr, hb, g2, be2, out, nullptr);
}